// Round 4
// baseline (238.294 us; speedup 1.0000x reference)
//
#include <hip/hip_runtime.h>
#include <hip/hip_bf16.h>
#include <math.h>
#include <stdint.h>

typedef unsigned short u16;
typedef __attribute__((ext_vector_type(8))) short bf16x8;
typedef __attribute__((ext_vector_type(4))) float f32x4;
typedef __attribute__((ext_vector_type(4))) unsigned short u16x4;
typedef __attribute__((ext_vector_type(4))) unsigned int uint32x4;

#define MFMA_BF16(A, B, C) __builtin_amdgcn_mfma_f32_16x16x32_bf16((A), (B), (C), 0, 0, 0)

__device__ __forceinline__ void async16(const void* g, const void* l) {
    __builtin_amdgcn_global_load_lds(
        (const __attribute__((address_space(1))) unsigned int*)(uintptr_t)g,
        (__attribute__((address_space(3))) unsigned int*)(uintptr_t)l, 16, 0, 0);
}

__device__ __forceinline__ u16 f2bf(float f) {
    unsigned u = __float_as_uint(f);
    u += 0x7fffu + ((u >> 16) & 1u);
    return (u16)(u >> 16);
}

__device__ __forceinline__ unsigned pack2(float a, float b) {
    __hip_bfloat162 h = __float22bfloat162_rn(float2{a, b});
    return *reinterpret_cast<unsigned*>(&h);
}

__device__ __forceinline__ float bf2f(u16 v) {
    unsigned u = ((unsigned)v) << 16;
    return __uint_as_float(u);
}

__device__ __forceinline__ bf16x8 mk_frag(unsigned w0, unsigned w1,
                                          unsigned w2, unsigned w3) {
    uint32x4 u = {w0, w1, w2, w3};
    return __builtin_bit_cast(bf16x8, u);
}

// ---------------------------------------------------------------------------
// Converters
// ---------------------------------------------------------------------------
__global__ __launch_bounds__(256) void cvt_x(const float* __restrict__ x,
                                             u16* __restrict__ xb) {
    int i = blockIdx.x * 256 + threadIdx.x;
    float4 v = ((const float4*)x)[i];
    u16x4 o = {f2bf(v.x), f2bf(v.y), f2bf(v.z), f2bf(v.w)};
    ((u16x4*)xb)[i] = o;
}

// All 4 weights fp32 [K=1024][N] -> bf16 [N][1024] in one launch.
__global__ __launch_bounds__(256) void cvt_w_all(
    const float* __restrict__ Wq, const float* __restrict__ Wks,
    const float* __restrict__ Wkl, const float* __restrict__ Wo,
    u16* __restrict__ wqt, u16* __restrict__ wkst,
    u16* __restrict__ wklt, u16* __restrict__ wot)
{
    __shared__ float tile[32][33];
    int x = blockIdx.x;
    const float* W; u16* Wt; int N, nb;
    if (x < 32)       { W = Wq;  Wt = wqt;  N = 1024; nb = x * 32; }
    else if (x < 96)  { W = Wks; Wt = wkst; N = 2048; nb = (x - 32) * 32; }
    else if (x < 160) { W = Wkl; Wt = wklt; N = 2048; nb = (x - 96) * 32; }
    else              { W = Wo;  Wt = wot;  N = 1024; nb = (x - 160) * 32; }
    int kb = blockIdx.y * 32;
    int t = threadIdx.x;
    int r = t >> 3, c4 = (t & 7) * 4;
    float4 v = *(const float4*)&W[(size_t)(kb + r) * N + nb + c4];
    tile[r][c4] = v.x; tile[r][c4 + 1] = v.y;
    tile[r][c4 + 2] = v.z; tile[r][c4 + 3] = v.w;
    __syncthreads();
    u16x4 o = {f2bf(tile[c4 + 0][r]), f2bf(tile[c4 + 1][r]),
               f2bf(tile[c4 + 2][r]), f2bf(tile[c4 + 3][r])};
    *(u16x4*)&Wt[(size_t)(nb + r) * 1024 + kb + c4] = o;
}

// ---------------------------------------------------------------------------
// Fused projection GEMM. Q pre-scaled by 0.125*log2(e).
// R4: block tile 128(tok) x 256(feat), 4 waves, each wave 64x128 output
// (acc 4x8): MFMA:ds_read density 32:12 (was 16:8), LDS bytes/FLOP -27%.
// 2-phase prefetch double-buffer: stage(kt+1) issued BEFORE compute(kt),
// ONE barrier per K-step -> load latency hides under the 32-MFMA phase
// (old structure exposed full latency every step: stage -> drain -> compute).
// K-type tiles compute C^T (m=features from Blds, n=tokens from Alds) ->
// u16x4 head-major stores. V-type compute C (m=tokens, n=features) ->
// u16x4 transposed [B,16,64,L] stores, token pi-permuted within 32-blocks
// so attn's PV B-fragment needs no cross-lane shuffle.
// ---------------------------------------------------------------------------
__global__ __launch_bounds__(256, 2) void gemm_proj(
    const u16* __restrict__ A, const u16* __restrict__ wq,
    const u16* __restrict__ wks, const u16* __restrict__ wkl,
    u16* __restrict__ qd, u16* __restrict__ ksd, u16* __restrict__ vsd,
    u16* __restrict__ kld, u16* __restrict__ vld)
{
    __shared__ u16 Alds[2][128][32];   // x rows (tokens)       16 KB
    __shared__ u16 Blds[2][256][32];   // W rows (features)     32 KB
    const int cx = blockIdx.x;         // 20 col-tiles of 256
    const u16* Bt; u16* dK; u16* dV; int colMat, colLoc; float osc = 1.0f;
    bool ktype;
    if (cx < 4) {
        Bt = wq; ktype = true; colLoc = cx * 256; colMat = colLoc;
        dK = qd; dV = nullptr; osc = 0.18033688f;
    } else if (cx < 12) {
        Bt = wks; ktype = (cx < 8);
        if (ktype) { colLoc = (cx - 4) * 256; colMat = colLoc; }
        else       { colLoc = (cx - 8) * 256; colMat = 1024 + colLoc; }
        dK = ksd; dV = vsd;
    } else {
        Bt = wkl; ktype = (cx < 16);
        if (ktype) { colLoc = (cx - 12) * 256; colMat = colLoc; }
        else       { colLoc = (cx - 16) * 256; colMat = 1024 + colLoc; }
        dK = kld; dV = vld;
    }

    const int t = threadIdx.x;
    const int l = t & 63, w = t >> 6;
    const int rowBase = blockIdx.y * 128;
    const int lc = l & 15, lr4 = l >> 4;

    f32x4 acc[4][8];
#pragma unroll
    for (int i = 0; i < 4; i++)
#pragma unroll
        for (int j = 0; j < 8; j++) acc[i][j] = (f32x4){0.f, 0.f, 0.f, 0.f};

    const int sl  = l >> 2;                       // row within 16-row chunk
    const int sc8 = (((l & 3) ^ (sl & 3)) * 8);   // pre-swizzled 16B slot
    // A: wave w stages rows w*32 + {0,16}; B: wave w stages rows w*64 + {0..48}
    const u16* Ag = A  + (size_t)(rowBase + w * 32 + sl) * 1024 + sc8;
    const u16* Bg = Bt + (size_t)(colMat  + w * 64 + sl) * 1024 + sc8;
    const int sw = (lc & 3);

    auto stage = [&](int kt, int buf) {
        const int ko = kt * 32;
        async16(Ag + ko,             &Alds[buf][w * 32][0]);
        async16(Ag + ko + 16 * 1024, &Alds[buf][w * 32 + 16][0]);
        async16(Bg + ko,             &Blds[buf][w * 64][0]);
        async16(Bg + ko + 16 * 1024, &Blds[buf][w * 64 + 16][0]);
        async16(Bg + ko + 32 * 1024, &Blds[buf][w * 64 + 32][0]);
        async16(Bg + ko + 48 * 1024, &Blds[buf][w * 64 + 48][0]);
    };

    const int mOff = ktype ? w * 64 : (w & 1) * 64;
    const int nOff = ktype ? 0      : (w >> 1) * 128;

    stage(0, 0);
    __syncthreads();

    for (int kt = 0; kt < 32; ++kt) {
        const int cur = kt & 1;
        if (kt + 1 < 32) stage(kt + 1, cur ^ 1);

        const u16 (*Ab)[32] = Alds[cur];
        const u16 (*Bb)[32] = Blds[cur];
        const u16 (*Lm)[32] = ktype ? Bb : Ab;
        const u16 (*Ln)[32] = ktype ? Ab : Bb;

        bf16x8 af[4], bf[8];
#pragma unroll
        for (int mt = 0; mt < 4; ++mt)
            af[mt] = *(const bf16x8*)&Lm[mOff + mt * 16 + lc][(lr4 ^ sw) * 8];
#pragma unroll
        for (int nt = 0; nt < 8; ++nt)
            bf[nt] = *(const bf16x8*)&Ln[nOff + nt * 16 + lc][(lr4 ^ sw) * 8];
#pragma unroll
        for (int mt = 0; mt < 4; ++mt)
#pragma unroll
            for (int nt = 0; nt < 8; ++nt)
                acc[mt][nt] = MFMA_BF16(af[mt], bf[nt], acc[mt][nt]);

        __syncthreads();
    }

    if (ktype) {
        // C^T: m = features (within colLoc..+255), n = tokens.
#pragma unroll
        for (int mt = 0; mt < 4; ++mt)
#pragma unroll
            for (int nt = 0; nt < 8; ++nt) {
                int f   = colLoc + w * 64 + mt * 16 + lr4 * 4;  // 0..1023
                int tok = rowBase + nt * 16 + lc;
                int b = tok >> 10, tk = tok & 1023;
                int head = (f >> 6) & 15, d = f & 63;
                u16x4 pv = {f2bf(acc[mt][nt][0] * osc), f2bf(acc[mt][nt][1] * osc),
                            f2bf(acc[mt][nt][2] * osc), f2bf(acc[mt][nt][3] * osc)};
                *(u16x4*)&dK[((size_t)(b * 16 + head) * 1024 + tk) * 64 + d] = pv;
            }
    } else {
        // C: m = tokens, n = features. Transposed V store [B,16,64,L],
        // token index pi-permuted within each 32-block (4-aligned groups).
#pragma unroll
        for (int mt = 0; mt < 4; ++mt)
#pragma unroll
            for (int nt = 0; nt < 8; ++nt) {
                int gr0 = rowBase + (w & 1) * 64 + mt * 16 + lr4 * 4;  // token
                int gc0 = colLoc + (w >> 1) * 128 + nt * 16;           // 0..1023
                int head = gc0 >> 6;                                   // 0..15
                int b = gr0 >> 10, tok = gr0 & 1023;
                int tokp = (tok & ~31) | (((tok >> 2) & 3) << 3) |
                           (((tok >> 4) & 1) << 2);
                int d = (gc0 & 63) + lc;
                u16x4 pv = {f2bf(acc[mt][nt][0]), f2bf(acc[mt][nt][1]),
                            f2bf(acc[mt][nt][2]), f2bf(acc[mt][nt][3])};
                *(u16x4*)&dV[((size_t)(b * 16 + head) * 64 + d) * 1024 +
                             tokp] = pv;
            }
    }
}

// ---------------------------------------------------------------------------
// Output GEMM: fp32 C = attn_bf16 x Wo^T, computed as C^T (A=Wo, B=attn).
// 64-token x 128-feature tiles -> 512 blocks (2/CU). float4 stores.
// ---------------------------------------------------------------------------
__global__ __launch_bounds__(256) void gemm_out(
    const u16* __restrict__ Aattn, const u16* __restrict__ Bwot,
    float* __restrict__ dst)
{
    __shared__ u16 Alds[64][32];    // tokens x k
    __shared__ u16 Blds[128][32];   // features x k
    const int t = threadIdx.x;
    const int l = t & 63, w = t >> 6;
    const int wm = w & 1, wn = w >> 1;          // wm: feature half, wn: token half
    const int rowBase = blockIdx.y * 64;        // tokens
    const int colBase = blockIdx.x * 128;       // features
    const int lc = l & 15, lr4 = l >> 4;

    f32x4 acc[4][2];
#pragma unroll
    for (int i = 0; i < 4; i++)
#pragma unroll
        for (int j = 0; j < 2; j++) acc[i][j] = (f32x4){0.f, 0.f, 0.f, 0.f};

    const int sl  = l >> 2;
    const int sc8 = (((l & 3) ^ (sl & 3)) * 8);
    const u16* Ag = Aattn + (size_t)(rowBase + w * 16 + sl) * 1024 + sc8;
    const u16* Bg = Bwot  + (size_t)(colBase + w * 32 + sl) * 1024 + sc8;
    const int sw = (lc & 3);

    for (int kt = 0; kt < 32; ++kt) {
        __syncthreads();
        const int ko = kt * 32;
        async16(Ag + ko,         &Alds[w * 16][0]);
        async16(Bg + ko,         &Blds[w * 32][0]);
        async16(Bg + ko + 16384, &Blds[w * 32 + 16][0]);
        __syncthreads();

        bf16x8 af[4], bf[2];
#pragma unroll
        for (int mt = 0; mt < 4; ++mt)
            af[mt] = *(const bf16x8*)&Blds[wm * 64 + mt * 16 + lc][(lr4 ^ sw) * 8];
#pragma unroll
        for (int nt = 0; nt < 2; ++nt)
            bf[nt] = *(const bf16x8*)&Alds[wn * 32 + nt * 16 + lc][(lr4 ^ sw) * 8];
#pragma unroll
        for (int mt = 0; mt < 4; ++mt)
#pragma unroll
            for (int nt = 0; nt < 2; ++nt)
                acc[mt][nt] = MFMA_BF16(af[mt], bf[nt], acc[mt][nt]);
    }

#pragma unroll
    for (int mt = 0; mt < 4; ++mt)
#pragma unroll
        for (int nt = 0; nt < 2; ++nt) {
            int f   = colBase + wm * 64 + mt * 16 + lr4 * 4;
            int tok = rowBase + wn * 32 + nt * 16 + lc;
            float4 v = {acc[mt][nt][0], acc[mt][nt][1],
                        acc[mt][nt][2], acc[mt][nt][3]};
            *(float4*)&dst[(size_t)tok * 1024 + f] = v;
        }
}

// ---------------------------------------------------------------------------
// Flash attention, transposed-MFMA (S^T, O^T), one branch per block,
// K/V double-buffered prefetch, one barrier/iter. Raw v_exp_f32.
// Branch 0 skips k-tiles with |q-k| > ~450 (decay weight < 2^-32).
// Zero-shuffle PV (pack2 words ARE the PV B-fragment; V pi-permuted by
// producer). Decay folded into MFMA C-init. launch_bounds (256,4).
// ---------------------------------------------------------------------------
__global__ __launch_bounds__(256, 4) void attn_mfma(
    const u16* __restrict__ Q, const u16* __restrict__ Ksb,
    const u16* __restrict__ Vsb, const u16* __restrict__ Klb,
    const u16* __restrict__ Vlb, const float* __restrict__ decayf,
    u16* __restrict__ Os, u16* __restrict__ Ol)
{
    __shared__ __align__(16) u16 Kt[2][2][64][32];  // [buf][d-half][krow][32d]
    __shared__ __align__(16) u16 Vt[2][2][64][32];  // [buf][k-half][d][32krow]

    const int t = threadIdx.x;
    const int l = t & 63, w = t >> 6;
    const int lc = l & 15, lr4 = l >> 4;
    const int h = blockIdx.x, qt = blockIdx.y;
    const int b = blockIdx.z >> 1, branch = blockIdx.z & 1;
    const size_t bh = (size_t)(b * 16 + h);
    const int qbase = qt * 128;
    const u16* Qg = Q + bh * (1024 * 64);
    const u16* Kg = (branch ? Klb : Ksb) + bh * (1024 * 64);
    const u16* Vg = (branch ? Vlb : Vsb) + bh * (64 * 1024);
    u16* outp = branch ? Ol : Os;

    const int sl = l >> 2;
    const int sc = (((l & 3) ^ ((l >> 3) & 3)) * 8);
    const int swr = (lc >> 1) & 3;

    // branch-0 range: only k-tiles with |q - k| < ~450 matter
    int ktLo = 0, ktHi = 16;
    if (branch == 0) {
        ktLo = qt * 2 - 7; if (ktLo < 0) ktLo = 0;
        ktHi = qt * 2 + 9; if (ktHi > 16) ktHi = 16;
    }

    // ---- Q B-operand fragments straight from global ----
    bf16x8 aQ[2][2];
#pragma unroll
    for (int qg = 0; qg < 2; ++qg)
#pragma unroll
        for (int kh = 0; kh < 2; ++kh)
            aQ[qg][kh] = *(const bf16x8*)&Qg[
                (size_t)(qbase + w * 32 + qg * 16 + lc) * 64 + kh * 32 + lr4 * 8];

    auto stage = [&](int kt, int buf) {
#pragma unroll
        for (int i = 0; i < 4; i++) {
            int id = w * 4 + i;
            int kh = (id >> 2) & 1, ch = id & 3;
            if (id < 8)
                async16(Kg + (size_t)(kt * 64 + ch * 16 + sl) * 64 + kh * 32 + sc,
                        &Kt[buf][kh][ch * 16][0]);
            else
                async16(Vg + (size_t)(ch * 16 + sl) * 1024 + kt * 64 + kh * 32 + sc,
                        &Vt[buf][kh][ch * 16][0]);
        }
    };

    stage(ktLo, 0);
    __syncthreads();

    const float C2 = (1.0f - decayf[0]) * 1.44269504f;
    const float qf = (float)(qbase + w * 32 + lc);

    f32x4 sumv[2] = {(f32x4){0.f, 0.f, 0.f, 0.f}, (f32x4){0.f, 0.f, 0.f, 0.f}};
    f32x4 o[2][4];
#pragma unroll
    for (int qg = 0; qg < 2; ++qg)
#pragma unroll
        for (int dt = 0; dt < 4; ++dt) o[qg][dt] = (f32x4){0.f, 0.f, 0.f, 0.f};

    for (int kt = ktLo, it = 0; kt < ktHi; ++kt, ++it) {
        const int cur = it & 1;
        if (kt + 1 < ktHi) stage(kt + 1, cur ^ 1);

        bf16x8 ak[4][2];
#pragma unroll
        for (int nt = 0; nt < 4; ++nt) {
            ak[nt][0] = *(const bf16x8*)&Kt[cur][0][nt * 16 + lc][(lr4 ^ swr) * 8];
            ak[nt][1] = *(const bf16x8*)&Kt[cur][1][nt * 16 + lc][(lr4 ^ swr) * 8];
        }

        unsigned pw[2][8];
#pragma unroll
        for (int qg = 0; qg < 2; ++qg) {
            const float d0 = qf + (float)(qg * 16 - kt * 64 - lr4 * 4);
            f32x4 s[4];
#pragma unroll
            for (int nt = 0; nt < 4; ++nt) {
                if (branch == 0) {
                    float dd = d0 - (float)(nt * 16);
                    s[nt] = (f32x4){-fabsf(dd) * C2,
                                    -fabsf(dd - 1.0f) * C2,
                                    -fabsf(dd - 2.0f) * C2,
                                    -fabsf(dd - 3.0f) * C2};
                } else {
                    s[nt] = (f32x4){0.f, 0.f, 0.f, 0.f};
                }
                s[nt] = MFMA_BF16(ak[nt][0], aQ[qg][0], s[nt]);
                s[nt] = MFMA_BF16(ak[nt][1], aQ[qg][1], s[nt]);
            }
#pragma unroll
            for (int nt = 0; nt < 4; ++nt) {
                float p0 = __builtin_amdgcn_exp2f(s[nt][0]);
                float p1 = __builtin_amdgcn_exp2f(s[nt][1]);
                float p2 = __builtin_amdgcn_exp2f(s[nt][2]);
                float p3 = __builtin_amdgcn_exp2f(s[nt][3]);
                sumv[qg][0] += p0; sumv[qg][1] += p1;
                sumv[qg][2] += p2; sumv[qg][3] += p3;
                pw[qg][nt * 2]     = pack2(p0, p1);
                pw[qg][nt * 2 + 1] = pack2(p2, p3);
            }
        }

#pragma unroll
        for (int dt = 0; dt < 4; ++dt) {
            bf16x8 v0 = *(const bf16x8*)&Vt[cur][0][dt * 16 + lc][(lr4 ^ swr) * 8];
            bf16x8 v1 = *(const bf16x8*)&Vt[cur][1][dt * 16 + lc][(lr4 ^ swr) * 8];
#pragma unroll
            for (int qg = 0; qg < 2; ++qg) {
                bf16x8 pb0 = mk_frag(pw[qg][0], pw[qg][1], pw[qg][2], pw[qg][3]);
                bf16x8 pb1 = mk_frag(pw[qg][4], pw[qg][5], pw[qg][6], pw[qg][7]);
                o[qg][dt] = MFMA_BF16(v0, pb0, o[qg][dt]);
                o[qg][dt] = MFMA_BF16(v1, pb1, o[qg][dt]);
            }
        }

        __syncthreads();
    }

#pragma unroll
    for (int qg = 0; qg < 2; ++qg) {
        float s = (sumv[qg][0] + sumv[qg][1]) + (sumv[qg][2] + sumv[qg][3]);
        s += __shfl_xor(s, 16);
        s += __shfl_xor(s, 32);
        float inv = 1.0f / s;
        int qrow = qbase + w * 32 + qg * 16 + lc;
        u16* op = outp + ((size_t)(b * 1024) + qrow) * 1024 + h * 64;
#pragma unroll
        for (int dt = 0; dt < 4; ++dt) {
            uint2 w2 = {pack2(o[qg][dt][0] * inv, o[qg][dt][1] * inv),
                        pack2(o[qg][dt][2] * inv, o[qg][dt][3] * inv)};
            *(uint2*)&op[dt * 16 + lr4 * 4] = w2;
        }
    }
}

// ---------------------------------------------------------------------------
// Mix: attn = alpha*Os + (1-alpha)*Ol, elementwise bf16.
// ---------------------------------------------------------------------------
__global__ __launch_bounds__(256) void mix_kernel(
    const u16* __restrict__ Os, const u16* __restrict__ Ol,
    const float* __restrict__ mixw, u16* __restrict__ dst)
{
    const float a = 1.0f / (1.0f + __expf(-mixw[0]));
    int i = blockIdx.x * 256 + threadIdx.x;
    uint4 s = ((const uint4*)Os)[i];
    uint4 l = ((const uint4*)Ol)[i];
    unsigned su[4] = {s.x, s.y, s.z, s.w};
    unsigned lu[4] = {l.x, l.y, l.z, l.w};
    unsigned ou[4];
#pragma unroll
    for (int k = 0; k < 4; ++k) {
        float s0 = bf2f((u16)su[k]), s1 = bf2f((u16)(su[k] >> 16));
        float l0 = bf2f((u16)lu[k]), l1 = bf2f((u16)(lu[k] >> 16));
        ou[k] = pack2(l0 + a * (s0 - l0), l1 + a * (s1 - l1));
    }
    ((uint4*)dst)[i] = make_uint4(ou[0], ou[1], ou[2], ou[3]);
}

// ---------------------------------------------------------------------------
extern "C" void kernel_launch(void* const* d_in, const int* in_sizes, int n_in,
                              void* d_out, int out_size, void* d_ws, size_t ws_size,
                              hipStream_t stream) {
    const float* x      = (const float*)d_in[0];
    const float* Wq     = (const float*)d_in[1];
    const float* Wkvs   = (const float*)d_in[2];
    const float* Wkvl   = (const float*)d_in[3];
    const float* Wo     = (const float*)d_in[4];
    const float* mixw   = (const float*)d_in[5];
    const float* decayf = (const float*)d_in[6];

    const size_t M1 = 1024 * 1024;
    u16* ws    = (u16*)d_ws;
    u16* xb    = ws;               // 4M  (reused as Os after gemm_proj)
    u16* wqt   = xb + 4 * M1;      // 1M  (wqt..wkvlt reused as Ol)
    u16* wkvst = wqt + 1 * M1;     // 2M
    u16* wkvlt = wkvst + 2 * M1;   // 2M
    u16* wot   = wkvlt + 2 * M1;   // 1M
    u16* qb    = wot + 1 * M1;     // 4M
    u16* ksb   = qb + 4 * M1;      // 4M
    u16* vsb   = ksb + 4 * M1;     // 4M  ([B,16,64,L], pi-permuted tokens)
    u16* klb   = vsb + 4 * M1;     // 4M
    u16* vlb   = klb + 4 * M1;     // 4M  (same)
    u16* attnb = vlb + 4 * M1;     // 4M
    u16* osb   = xb;               // alias: free after gemm_proj
    u16* olb   = wqt;              // alias: free after gemm_proj

    cvt_x<<<4096, 256, 0, stream>>>(x, xb);
    cvt_w_all<<<dim3(192, 32), 256, 0, stream>>>(Wq, Wkvs, Wkvl, Wo,
                                                 wqt, wkvst, wkvlt, wot);
    gemm_proj<<<dim3(20, 32), 256, 0, stream>>>(xb, wqt, wkvst, wkvlt,
                                                qb, ksb, vsb, klb, vlb);
    attn_mfma<<<dim3(16, 8, 8), 256, 0, stream>>>(qb, ksb, vsb, klb, vlb,
                                                  decayf, osb, olb);
    mix_kernel<<<2048, 256, 0, stream>>>(osb, olb, mixw, attnb);
    gemm_out<<<dim3(8, 64), 256, 0, stream>>>(attnb, wot, (float*)d_out);
}

// Round 5
// 236.011 us; speedup vs baseline: 1.0097x; 1.0097x over previous
//
#include <hip/hip_runtime.h>
#include <hip/hip_bf16.h>
#include <math.h>
#include <stdint.h>

typedef unsigned short u16;
typedef __attribute__((ext_vector_type(8))) short bf16x8;
typedef __attribute__((ext_vector_type(4))) float f32x4;
typedef __attribute__((ext_vector_type(4))) unsigned short u16x4;
typedef __attribute__((ext_vector_type(4))) unsigned int uint32x4;

#define MFMA_BF16(A, B, C) __builtin_amdgcn_mfma_f32_16x16x32_bf16((A), (B), (C), 0, 0, 0)

__device__ __forceinline__ void async16(const void* g, const void* l) {
    __builtin_amdgcn_global_load_lds(
        (const __attribute__((address_space(1))) unsigned int*)(uintptr_t)g,
        (__attribute__((address_space(3))) unsigned int*)(uintptr_t)l, 16, 0, 0);
}

__device__ __forceinline__ u16 f2bf(float f) {
    unsigned u = __float_as_uint(f);
    u += 0x7fffu + ((u >> 16) & 1u);
    return (u16)(u >> 16);
}

__device__ __forceinline__ unsigned pack2(float a, float b) {
    __hip_bfloat162 h = __float22bfloat162_rn(float2{a, b});
    return *reinterpret_cast<unsigned*>(&h);
}

__device__ __forceinline__ float bf2f(u16 v) {
    unsigned u = ((unsigned)v) << 16;
    return __uint_as_float(u);
}

__device__ __forceinline__ bf16x8 mk_frag(unsigned w0, unsigned w1,
                                          unsigned w2, unsigned w3) {
    uint32x4 u = {w0, w1, w2, w3};
    return __builtin_bit_cast(bf16x8, u);
}

// ---------------------------------------------------------------------------
// Converters
// ---------------------------------------------------------------------------
__global__ __launch_bounds__(256) void cvt_x(const float* __restrict__ x,
                                             u16* __restrict__ xb) {
    int i = blockIdx.x * 256 + threadIdx.x;
    float4 v = ((const float4*)x)[i];
    u16x4 o = {f2bf(v.x), f2bf(v.y), f2bf(v.z), f2bf(v.w)};
    ((u16x4*)xb)[i] = o;
}

// All 4 weights fp32 [K=1024][N] -> bf16 [N][1024] in one launch.
__global__ __launch_bounds__(256) void cvt_w_all(
    const float* __restrict__ Wq, const float* __restrict__ Wks,
    const float* __restrict__ Wkl, const float* __restrict__ Wo,
    u16* __restrict__ wqt, u16* __restrict__ wkst,
    u16* __restrict__ wklt, u16* __restrict__ wot)
{
    __shared__ float tile[32][33];
    int x = blockIdx.x;
    const float* W; u16* Wt; int N, nb;
    if (x < 32)       { W = Wq;  Wt = wqt;  N = 1024; nb = x * 32; }
    else if (x < 96)  { W = Wks; Wt = wkst; N = 2048; nb = (x - 32) * 32; }
    else if (x < 160) { W = Wkl; Wt = wklt; N = 2048; nb = (x - 96) * 32; }
    else              { W = Wo;  Wt = wot;  N = 1024; nb = (x - 160) * 32; }
    int kb = blockIdx.y * 32;
    int t = threadIdx.x;
    int r = t >> 3, c4 = (t & 7) * 4;
    float4 v = *(const float4*)&W[(size_t)(kb + r) * N + nb + c4];
    tile[r][c4] = v.x; tile[r][c4 + 1] = v.y;
    tile[r][c4 + 2] = v.z; tile[r][c4 + 3] = v.w;
    __syncthreads();
    u16x4 o = {f2bf(tile[c4 + 0][r]), f2bf(tile[c4 + 1][r]),
               f2bf(tile[c4 + 2][r]), f2bf(tile[c4 + 3][r])};
    *(u16x4*)&Wt[(size_t)(nb + r) * 1024 + kb + c4] = o;
}

// ---------------------------------------------------------------------------
// Fused projection GEMM. Q pre-scaled by 0.125*log2(e).
// R5: 128x128 tile, acc 4x4 (64 AGPR + ~90 VGPR unified ~150 ->
// 3 waves/SIMD co-resident, launch_bounds(256,3)), PLUS 2-deep prefetch
// double-buffer (stage kt+1 before compute kt, one barrier/step), PLUS
// bijective XCD swizzle (nwg=1280, 1280%8==0): each XCD owns 4 row-tiles x
// all 40 col-tiles -> the shared 1MB A-chunk stays hot in its private L2.
// R4's 128x256 tile collapsed occupancy (acc 4x8 = 128 AGPR; unified regs
// ~224 -> 2 waves/SIMD) and was perf-neutral: ILP gain == TLP loss.
// K-type tiles compute C^T -> u16x4 head-major stores. V-type compute C ->
// u16x4 transposed [B,16,64,L] stores, token pi-permuted within 32-blocks
// so attn's PV B-fragment needs no cross-lane shuffle.
// ---------------------------------------------------------------------------
__global__ __launch_bounds__(256, 3) void gemm_proj(
    const u16* __restrict__ A, const u16* __restrict__ wq,
    const u16* __restrict__ wks, const u16* __restrict__ wkl,
    u16* __restrict__ qd, u16* __restrict__ ksd, u16* __restrict__ vsd,
    u16* __restrict__ kld, u16* __restrict__ vld)
{
    __shared__ u16 Alds[2][128][32];   // x rows (tokens)     16 KB
    __shared__ u16 Blds[2][128][32];   // W rows (features)   16 KB

    // XCD-aware bijective swizzle: dispatch id -> work id.
    const int wg  = blockIdx.y * 40 + blockIdx.x;      // 1280 blocks
    const int swz = (wg & 7) * 160 + (wg >> 3);        // 1280/8 = 160
    const int cx  = swz % 40;
    const int rowBase = (swz / 40) * 128;

    const u16* Bt; u16* dK; u16* dV; int colBase; float osc = 1.0f;
    bool ktype;
    if (cx < 8)       { Bt = wq;  colBase = cx * 128;        dK = qd;  dV = nullptr;
                        osc = 0.18033688f; ktype = true; }
    else if (cx < 24) { Bt = wks; colBase = (cx - 8) * 128;  dK = ksd; dV = vsd;
                        ktype = (cx < 16); }
    else              { Bt = wkl; colBase = (cx - 24) * 128; dK = kld; dV = vld;
                        ktype = (cx < 32); }

    const int t = threadIdx.x;
    const int l = t & 63, w = t >> 6;
    const int wm = w & 1, wn = w >> 1;
    const int lc = l & 15, lr4 = l >> 4;

    f32x4 acc[4][4];
#pragma unroll
    for (int i = 0; i < 4; i++)
#pragma unroll
        for (int j = 0; j < 4; j++) acc[i][j] = (f32x4){0.f, 0.f, 0.f, 0.f};

    const int srow = w * 32 + (l >> 2);
    const int sc8  = (((l & 3) ^ ((l >> 2) & 3)) * 8);
    const u16* Ag = A  + (size_t)(rowBase + srow) * 1024 + sc8;
    const u16* Bg = Bt + (size_t)(colBase + srow) * 1024 + sc8;
    const int sw = (lc & 3);

    // m-index operand / n-index operand (swapped for ktype -> C^T)
    auto stage = [&](int kt, int buf) {
        const int ko = kt * 32;
        async16(Ag + ko,         &Alds[buf][w * 32][0]);
        async16(Ag + ko + 16384, &Alds[buf][w * 32 + 16][0]);
        async16(Bg + ko,         &Blds[buf][w * 32][0]);
        async16(Bg + ko + 16384, &Blds[buf][w * 32 + 16][0]);
    };

    stage(0, 0);
    __syncthreads();

    for (int kt = 0; kt < 32; ++kt) {
        const int cur = kt & 1;
        if (kt + 1 < 32) stage(kt + 1, cur ^ 1);

        const u16 (*Lm)[32] = ktype ? Blds[cur] : Alds[cur];
        const u16 (*Ln)[32] = ktype ? Alds[cur] : Blds[cur];

        bf16x8 af[4], bf[4];
#pragma unroll
        for (int mt = 0; mt < 4; ++mt)
            af[mt] = *(const bf16x8*)&Lm[wm * 64 + mt * 16 + lc][(lr4 ^ sw) * 8];
#pragma unroll
        for (int nt = 0; nt < 4; ++nt)
            bf[nt] = *(const bf16x8*)&Ln[wn * 64 + nt * 16 + lc][(lr4 ^ sw) * 8];
#pragma unroll
        for (int mt = 0; mt < 4; ++mt)
#pragma unroll
            for (int nt = 0; nt < 4; ++nt)
                acc[mt][nt] = MFMA_BF16(af[mt], bf[nt], acc[mt][nt]);

        __syncthreads();
    }

    if (ktype) {
        // C^T: m = features, n = tokens. Lane holds 4 consecutive d.
#pragma unroll
        for (int mt = 0; mt < 4; ++mt)
#pragma unroll
            for (int nt = 0; nt < 4; ++nt) {
                int f   = colBase + wm * 64 + mt * 16 + lr4 * 4;
                int tok = rowBase + wn * 64 + nt * 16 + lc;
                int b = tok >> 10, tk = tok & 1023;
                int head = (f >> 6) & 15, d = f & 63;
                u16x4 pv = {f2bf(acc[mt][nt][0] * osc), f2bf(acc[mt][nt][1] * osc),
                            f2bf(acc[mt][nt][2] * osc), f2bf(acc[mt][nt][3] * osc)};
                *(u16x4*)&dK[((size_t)(b * 16 + head) * 1024 + tk) * 64 + d] = pv;
            }
    } else {
        // C: m = tokens, n = features. Transposed V store [B,16,64,L],
        // token index pi-permuted within each 32-block (4-aligned groups).
#pragma unroll
        for (int mt = 0; mt < 4; ++mt)
#pragma unroll
            for (int nt = 0; nt < 4; ++nt) {
                int gr0 = rowBase + wm * 64 + mt * 16 + lr4 * 4;
                int gc0 = colBase + wn * 64 + nt * 16;
                int head = gc0 >> 6;            // 16..31
                int b = gr0 >> 10, tok = gr0 & 1023;
                int tokp = (tok & ~31) | (((tok >> 2) & 3) << 3) |
                           (((tok >> 4) & 1) << 2);
                int d = (gc0 & 63) + lc;
                u16x4 pv = {f2bf(acc[mt][nt][0]), f2bf(acc[mt][nt][1]),
                            f2bf(acc[mt][nt][2]), f2bf(acc[mt][nt][3])};
                *(u16x4*)&dV[((size_t)(b * 16 + head - 16) * 64 + d) * 1024 +
                             tokp] = pv;
            }
    }
}

// ---------------------------------------------------------------------------
// Output GEMM: fp32 C = attn_bf16 x Wo^T, computed as C^T (A=Wo, B=attn).
// 64-token x 128-feature tiles -> 512 blocks (2/CU). float4 stores.
// R5: XCD-aware bijective swizzle (512%8==0) for A-token-chunk L2 locality.
// ---------------------------------------------------------------------------
__global__ __launch_bounds__(256) void gemm_out(
    const u16* __restrict__ Aattn, const u16* __restrict__ Bwot,
    float* __restrict__ dst)
{
    __shared__ u16 Alds[64][32];    // tokens x k
    __shared__ u16 Blds[128][32];   // features x k
    const int t = threadIdx.x;
    const int l = t & 63, w = t >> 6;
    const int wm = w & 1, wn = w >> 1;          // wm: feature half, wn: token half

    const int wg  = blockIdx.y * 8 + blockIdx.x;   // 512 blocks
    const int swz = (wg & 7) * 64 + (wg >> 3);
    const int rowBase = (swz >> 3) * 64;        // tokens
    const int colBase = (swz & 7) * 128;        // features

    const int lc = l & 15, lr4 = l >> 4;

    f32x4 acc[4][2];
#pragma unroll
    for (int i = 0; i < 4; i++)
#pragma unroll
        for (int j = 0; j < 2; j++) acc[i][j] = (f32x4){0.f, 0.f, 0.f, 0.f};

    const int sl  = l >> 2;
    const int sc8 = (((l & 3) ^ (sl & 3)) * 8);
    const u16* Ag = Aattn + (size_t)(rowBase + w * 16 + sl) * 1024 + sc8;
    const u16* Bg = Bwot  + (size_t)(colBase + w * 32 + sl) * 1024 + sc8;
    const int sw = (lc & 3);

    for (int kt = 0; kt < 32; ++kt) {
        __syncthreads();
        const int ko = kt * 32;
        async16(Ag + ko,         &Alds[w * 16][0]);
        async16(Bg + ko,         &Blds[w * 32][0]);
        async16(Bg + ko + 16384, &Blds[w * 32 + 16][0]);
        __syncthreads();

        bf16x8 af[4], bf[2];
#pragma unroll
        for (int mt = 0; mt < 4; ++mt)
            af[mt] = *(const bf16x8*)&Blds[wm * 64 + mt * 16 + lc][(lr4 ^ sw) * 8];
#pragma unroll
        for (int nt = 0; nt < 2; ++nt)
            bf[nt] = *(const bf16x8*)&Alds[wn * 32 + nt * 16 + lc][(lr4 ^ sw) * 8];
#pragma unroll
        for (int mt = 0; mt < 4; ++mt)
#pragma unroll
            for (int nt = 0; nt < 2; ++nt)
                acc[mt][nt] = MFMA_BF16(af[mt], bf[nt], acc[mt][nt]);
    }

#pragma unroll
    for (int mt = 0; mt < 4; ++mt)
#pragma unroll
        for (int nt = 0; nt < 2; ++nt) {
            int f   = colBase + wm * 64 + mt * 16 + lr4 * 4;
            int tok = rowBase + wn * 32 + nt * 16 + lc;
            float4 v = {acc[mt][nt][0], acc[mt][nt][1],
                        acc[mt][nt][2], acc[mt][nt][3]};
            *(float4*)&dst[(size_t)tok * 1024 + f] = v;
        }
}

// ---------------------------------------------------------------------------
// Flash attention, transposed-MFMA (S^T, O^T), one branch per block,
// K/V double-buffered prefetch, one barrier/iter. Raw v_exp_f32.
// Branch 0 skips k-tiles with |q-k| > ~450 (decay weight < 2^-32).
// Zero-shuffle PV (pack2 words ARE the PV B-fragment; V pi-permuted by
// producer). Decay folded into MFMA C-init. launch_bounds (256,4).
// ---------------------------------------------------------------------------
__global__ __launch_bounds__(256, 4) void attn_mfma(
    const u16* __restrict__ Q, const u16* __restrict__ Ksb,
    const u16* __restrict__ Vsb, const u16* __restrict__ Klb,
    const u16* __restrict__ Vlb, const float* __restrict__ decayf,
    u16* __restrict__ Os, u16* __restrict__ Ol)
{
    __shared__ __align__(16) u16 Kt[2][2][64][32];  // [buf][d-half][krow][32d]
    __shared__ __align__(16) u16 Vt[2][2][64][32];  // [buf][k-half][d][32krow]

    const int t = threadIdx.x;
    const int l = t & 63, w = t >> 6;
    const int lc = l & 15, lr4 = l >> 4;
    const int h = blockIdx.x, qt = blockIdx.y;
    const int b = blockIdx.z >> 1, branch = blockIdx.z & 1;
    const size_t bh = (size_t)(b * 16 + h);
    const int qbase = qt * 128;
    const u16* Qg = Q + bh * (1024 * 64);
    const u16* Kg = (branch ? Klb : Ksb) + bh * (1024 * 64);
    const u16* Vg = (branch ? Vlb : Vsb) + bh * (64 * 1024);
    u16* outp = branch ? Ol : Os;

    const int sl = l >> 2;
    const int sc = (((l & 3) ^ ((l >> 3) & 3)) * 8);
    const int swr = (lc >> 1) & 3;

    // branch-0 range: only k-tiles with |q - k| < ~450 matter
    int ktLo = 0, ktHi = 16;
    if (branch == 0) {
        ktLo = qt * 2 - 7; if (ktLo < 0) ktLo = 0;
        ktHi = qt * 2 + 9; if (ktHi > 16) ktHi = 16;
    }

    // ---- Q B-operand fragments straight from global ----
    bf16x8 aQ[2][2];
#pragma unroll
    for (int qg = 0; qg < 2; ++qg)
#pragma unroll
        for (int kh = 0; kh < 2; ++kh)
            aQ[qg][kh] = *(const bf16x8*)&Qg[
                (size_t)(qbase + w * 32 + qg * 16 + lc) * 64 + kh * 32 + lr4 * 8];

    auto stage = [&](int kt, int buf) {
#pragma unroll
        for (int i = 0; i < 4; i++) {
            int id = w * 4 + i;
            int kh = (id >> 2) & 1, ch = id & 3;
            if (id < 8)
                async16(Kg + (size_t)(kt * 64 + ch * 16 + sl) * 64 + kh * 32 + sc,
                        &Kt[buf][kh][ch * 16][0]);
            else
                async16(Vg + (size_t)(ch * 16 + sl) * 1024 + kt * 64 + kh * 32 + sc,
                        &Vt[buf][kh][ch * 16][0]);
        }
    };

    stage(ktLo, 0);
    __syncthreads();

    const float C2 = (1.0f - decayf[0]) * 1.44269504f;
    const float qf = (float)(qbase + w * 32 + lc);

    f32x4 sumv[2] = {(f32x4){0.f, 0.f, 0.f, 0.f}, (f32x4){0.f, 0.f, 0.f, 0.f}};
    f32x4 o[2][4];
#pragma unroll
    for (int qg = 0; qg < 2; ++qg)
#pragma unroll
        for (int dt = 0; dt < 4; ++dt) o[qg][dt] = (f32x4){0.f, 0.f, 0.f, 0.f};

    for (int kt = ktLo, it = 0; kt < ktHi; ++kt, ++it) {
        const int cur = it & 1;
        if (kt + 1 < ktHi) stage(kt + 1, cur ^ 1);

        bf16x8 ak[4][2];
#pragma unroll
        for (int nt = 0; nt < 4; ++nt) {
            ak[nt][0] = *(const bf16x8*)&Kt[cur][0][nt * 16 + lc][(lr4 ^ swr) * 8];
            ak[nt][1] = *(const bf16x8*)&Kt[cur][1][nt * 16 + lc][(lr4 ^ swr) * 8];
        }

        unsigned pw[2][8];
#pragma unroll
        for (int qg = 0; qg < 2; ++qg) {
            const float d0 = qf + (float)(qg * 16 - kt * 64 - lr4 * 4);
            f32x4 s[4];
#pragma unroll
            for (int nt = 0; nt < 4; ++nt) {
                if (branch == 0) {
                    float dd = d0 - (float)(nt * 16);
                    s[nt] = (f32x4){-fabsf(dd) * C2,
                                    -fabsf(dd - 1.0f) * C2,
                                    -fabsf(dd - 2.0f) * C2,
                                    -fabsf(dd - 3.0f) * C2};
                } else {
                    s[nt] = (f32x4){0.f, 0.f, 0.f, 0.f};
                }
                s[nt] = MFMA_BF16(ak[nt][0], aQ[qg][0], s[nt]);
                s[nt] = MFMA_BF16(ak[nt][1], aQ[qg][1], s[nt]);
            }
#pragma unroll
            for (int nt = 0; nt < 4; ++nt) {
                float p0 = __builtin_amdgcn_exp2f(s[nt][0]);
                float p1 = __builtin_amdgcn_exp2f(s[nt][1]);
                float p2 = __builtin_amdgcn_exp2f(s[nt][2]);
                float p3 = __builtin_amdgcn_exp2f(s[nt][3]);
                sumv[qg][0] += p0; sumv[qg][1] += p1;
                sumv[qg][2] += p2; sumv[qg][3] += p3;
                pw[qg][nt * 2]     = pack2(p0, p1);
                pw[qg][nt * 2 + 1] = pack2(p2, p3);
            }
        }

#pragma unroll
        for (int dt = 0; dt < 4; ++dt) {
            bf16x8 v0 = *(const bf16x8*)&Vt[cur][0][dt * 16 + lc][(lr4 ^ swr) * 8];
            bf16x8 v1 = *(const bf16x8*)&Vt[cur][1][dt * 16 + lc][(lr4 ^ swr) * 8];
#pragma unroll
            for (int qg = 0; qg < 2; ++qg) {
                bf16x8 pb0 = mk_frag(pw[qg][0], pw[qg][1], pw[qg][2], pw[qg][3]);
                bf16x8 pb1 = mk_frag(pw[qg][4], pw[qg][5], pw[qg][6], pw[qg][7]);
                o[qg][dt] = MFMA_BF16(v0, pb0, o[qg][dt]);
                o[qg][dt] = MFMA_BF16(v1, pb1, o[qg][dt]);
            }
        }

        __syncthreads();
    }

#pragma unroll
    for (int qg = 0; qg < 2; ++qg) {
        float s = (sumv[qg][0] + sumv[qg][1]) + (sumv[qg][2] + sumv[qg][3]);
        s += __shfl_xor(s, 16);
        s += __shfl_xor(s, 32);
        float inv = 1.0f / s;
        int qrow = qbase + w * 32 + qg * 16 + lc;
        u16* op = outp + ((size_t)(b * 1024) + qrow) * 1024 + h * 64;
#pragma unroll
        for (int dt = 0; dt < 4; ++dt) {
            uint2 w2 = {pack2(o[qg][dt][0] * inv, o[qg][dt][1] * inv),
                        pack2(o[qg][dt][2] * inv, o[qg][dt][3] * inv)};
            *(uint2*)&op[dt * 16 + lr4 * 4] = w2;
        }
    }
}

// ---------------------------------------------------------------------------
// Mix: attn = alpha*Os + (1-alpha)*Ol, elementwise bf16.
// ---------------------------------------------------------------------------
__global__ __launch_bounds__(256) void mix_kernel(
    const u16* __restrict__ Os, const u16* __restrict__ Ol,
    const float* __restrict__ mixw, u16* __restrict__ dst)
{
    const float a = 1.0f / (1.0f + __expf(-mixw[0]));
    int i = blockIdx.x * 256 + threadIdx.x;
    uint4 s = ((const uint4*)Os)[i];
    uint4 l = ((const uint4*)Ol)[i];
    unsigned su[4] = {s.x, s.y, s.z, s.w};
    unsigned lu[4] = {l.x, l.y, l.z, l.w};
    unsigned ou[4];
#pragma unroll
    for (int k = 0; k < 4; ++k) {
        float s0 = bf2f((u16)su[k]), s1 = bf2f((u16)(su[k] >> 16));
        float l0 = bf2f((u16)lu[k]), l1 = bf2f((u16)(lu[k] >> 16));
        ou[k] = pack2(l0 + a * (s0 - l0), l1 + a * (s1 - l1));
    }
    ((uint4*)dst)[i] = make_uint4(ou[0], ou[1], ou[2], ou[3]);
}

// ---------------------------------------------------------------------------
extern "C" void kernel_launch(void* const* d_in, const int* in_sizes, int n_in,
                              void* d_out, int out_size, void* d_ws, size_t ws_size,
                              hipStream_t stream) {
    const float* x      = (const float*)d_in[0];
    const float* Wq     = (const float*)d_in[1];
    const float* Wkvs   = (const float*)d_in[2];
    const float* Wkvl   = (const float*)d_in[3];
    const float* Wo     = (const float*)d_in[4];
    const float* mixw   = (const float*)d_in[5];
    const float* decayf = (const float*)d_in[6];

    const size_t M1 = 1024 * 1024;
    u16* ws    = (u16*)d_ws;
    u16* xb    = ws;               // 4M  (reused as Os after gemm_proj)
    u16* wqt   = xb + 4 * M1;      // 1M  (wqt..wkvlt reused as Ol)
    u16* wkvst = wqt + 1 * M1;     // 2M
    u16* wkvlt = wkvst + 2 * M1;   // 2M
    u16* wot   = wkvlt + 2 * M1;   // 1M
    u16* qb    = wot + 1 * M1;     // 4M
    u16* ksb   = qb + 4 * M1;      // 4M
    u16* vsb   = ksb + 4 * M1;     // 4M  ([B,16,64,L], pi-permuted tokens)
    u16* klb   = vsb + 4 * M1;     // 4M
    u16* vlb   = klb + 4 * M1;     // 4M  (same)
    u16* attnb = vlb + 4 * M1;     // 4M
    u16* osb   = xb;               // alias: free after gemm_proj
    u16* olb   = wqt;              // alias: free after gemm_proj

    cvt_x<<<4096, 256, 0, stream>>>(x, xb);
    cvt_w_all<<<dim3(192, 32), 256, 0, stream>>>(Wq, Wkvs, Wkvl, Wo,
                                                 wqt, wkvst, wkvlt, wot);
    gemm_proj<<<dim3(40, 32), 256, 0, stream>>>(xb, wqt, wkvst, wkvlt,
                                                qb, ksb, vsb, klb, vlb);
    attn_mfma<<<dim3(16, 8, 8), 256, 0, stream>>>(qb, ksb, vsb, klb, vlb,
                                                  decayf, osb, olb);
    mix_kernel<<<2048, 256, 0, stream>>>(osb, olb, mixw, attnb);
    gemm_out<<<dim3(8, 64), 256, 0, stream>>>(attnb, wot, (float*)d_out);
}

// Round 6
// 227.169 us; speedup vs baseline: 1.0490x; 1.0389x over previous
//
#include <hip/hip_runtime.h>
#include <hip/hip_bf16.h>
#include <math.h>
#include <stdint.h>

typedef unsigned short u16;
typedef __attribute__((ext_vector_type(8))) short bf16x8;
typedef __attribute__((ext_vector_type(4))) float f32x4;
typedef __attribute__((ext_vector_type(4))) unsigned short u16x4;
typedef __attribute__((ext_vector_type(4))) unsigned int uint32x4;

#define MFMA_BF16(A, B, C) __builtin_amdgcn_mfma_f32_16x16x32_bf16((A), (B), (C), 0, 0, 0)

__device__ __forceinline__ void async16(const void* g, const void* l) {
    __builtin_amdgcn_global_load_lds(
        (const __attribute__((address_space(1))) unsigned int*)(uintptr_t)g,
        (__attribute__((address_space(3))) unsigned int*)(uintptr_t)l, 16, 0, 0);
}

__device__ __forceinline__ u16 f2bf(float f) {
    unsigned u = __float_as_uint(f);
    u += 0x7fffu + ((u >> 16) & 1u);
    return (u16)(u >> 16);
}

__device__ __forceinline__ unsigned pack2(float a, float b) {
    __hip_bfloat162 h = __float22bfloat162_rn(float2{a, b});
    return *reinterpret_cast<unsigned*>(&h);
}

__device__ __forceinline__ float bf2f(u16 v) {
    unsigned u = ((unsigned)v) << 16;
    return __uint_as_float(u);
}

__device__ __forceinline__ bf16x8 mk_frag(unsigned w0, unsigned w1,
                                          unsigned w2, unsigned w3) {
    uint32x4 u = {w0, w1, w2, w3};
    return __builtin_bit_cast(bf16x8, u);
}

// ---------------------------------------------------------------------------
// Converters
// ---------------------------------------------------------------------------
__global__ __launch_bounds__(256) void cvt_x(const float* __restrict__ x,
                                             u16* __restrict__ xb) {
    int i = blockIdx.x * 256 + threadIdx.x;
    float4 v = ((const float4*)x)[i];
    u16x4 o = {f2bf(v.x), f2bf(v.y), f2bf(v.z), f2bf(v.w)};
    ((u16x4*)xb)[i] = o;
}

// All 4 weights fp32 [K=1024][N] -> bf16 [N][1024] in one launch.
__global__ __launch_bounds__(256) void cvt_w_all(
    const float* __restrict__ Wq, const float* __restrict__ Wks,
    const float* __restrict__ Wkl, const float* __restrict__ Wo,
    u16* __restrict__ wqt, u16* __restrict__ wkst,
    u16* __restrict__ wklt, u16* __restrict__ wot)
{
    __shared__ float tile[32][33];
    int x = blockIdx.x;
    const float* W; u16* Wt; int N, nb;
    if (x < 32)       { W = Wq;  Wt = wqt;  N = 1024; nb = x * 32; }
    else if (x < 96)  { W = Wks; Wt = wkst; N = 2048; nb = (x - 32) * 32; }
    else if (x < 160) { W = Wkl; Wt = wklt; N = 2048; nb = (x - 96) * 32; }
    else              { W = Wo;  Wt = wot;  N = 1024; nb = (x - 160) * 32; }
    int kb = blockIdx.y * 32;
    int t = threadIdx.x;
    int r = t >> 3, c4 = (t & 7) * 4;
    float4 v = *(const float4*)&W[(size_t)(kb + r) * N + nb + c4];
    tile[r][c4] = v.x; tile[r][c4 + 1] = v.y;
    tile[r][c4 + 2] = v.z; tile[r][c4 + 3] = v.w;
    __syncthreads();
    u16x4 o = {f2bf(tile[c4 + 0][r]), f2bf(tile[c4 + 1][r]),
               f2bf(tile[c4 + 2][r]), f2bf(tile[c4 + 3][r])};
    *(u16x4*)&Wt[(size_t)(nb + r) * 1024 + kb + c4] = o;
}

// ---------------------------------------------------------------------------
// Fused projection GEMM. Q pre-scaled by 0.125*log2(e).
// R6: NATURAL dispatch order restored. With grid (40,32), XCD = wg%8 = cx%8
// (40*y == 0 mod 8): each weight col-panel is pinned to one XCD -> weights
// (10 MB) stay hot in that XCD's private L2 across all 32 row-stripes
// (R3 measured FETCH 44 MB). R5's explicit swizzle made every XCD sweep all
// 40 col-tiles -> 8x weight re-fetch (FETCH 104 MB). Keep R5's structure:
// 128x128 tile, acc 4x4, (256,3) = 3 waves/SIMD, 2-deep prefetch dbuf
// (stage kt+1 before compute kt, one barrier per K-step).
// K-type tiles compute C^T -> u16x4 head-major stores. V-type compute C ->
// u16x4 transposed [B,16,64,L] stores, token pi-permuted within 32-blocks
// so attn's PV B-fragment needs no cross-lane shuffle.
// ---------------------------------------------------------------------------
__global__ __launch_bounds__(256, 3) void gemm_proj(
    const u16* __restrict__ A, const u16* __restrict__ wq,
    const u16* __restrict__ wks, const u16* __restrict__ wkl,
    u16* __restrict__ qd, u16* __restrict__ ksd, u16* __restrict__ vsd,
    u16* __restrict__ kld, u16* __restrict__ vld)
{
    __shared__ u16 Alds[2][128][32];   // x rows (tokens)     16 KB
    __shared__ u16 Blds[2][128][32];   // W rows (features)   16 KB

    const int cx = blockIdx.x;
    const int rowBase = blockIdx.y * 128;

    const u16* Bt; u16* dK; u16* dV; int colBase; float osc = 1.0f;
    bool ktype;
    if (cx < 8)       { Bt = wq;  colBase = cx * 128;        dK = qd;  dV = nullptr;
                        osc = 0.18033688f; ktype = true; }
    else if (cx < 24) { Bt = wks; colBase = (cx - 8) * 128;  dK = ksd; dV = vsd;
                        ktype = (cx < 16); }
    else              { Bt = wkl; colBase = (cx - 24) * 128; dK = kld; dV = vld;
                        ktype = (cx < 32); }

    const int t = threadIdx.x;
    const int l = t & 63, w = t >> 6;
    const int wm = w & 1, wn = w >> 1;
    const int lc = l & 15, lr4 = l >> 4;

    f32x4 acc[4][4];
#pragma unroll
    for (int i = 0; i < 4; i++)
#pragma unroll
        for (int j = 0; j < 4; j++) acc[i][j] = (f32x4){0.f, 0.f, 0.f, 0.f};

    const int srow = w * 32 + (l >> 2);
    const int sc8  = (((l & 3) ^ ((l >> 2) & 3)) * 8);
    const u16* Ag = A  + (size_t)(rowBase + srow) * 1024 + sc8;
    const u16* Bg = Bt + (size_t)(colBase + srow) * 1024 + sc8;
    const int sw = (lc & 3);

    auto stage = [&](int kt, int buf) {
        const int ko = kt * 32;
        async16(Ag + ko,         &Alds[buf][w * 32][0]);
        async16(Ag + ko + 16384, &Alds[buf][w * 32 + 16][0]);
        async16(Bg + ko,         &Blds[buf][w * 32][0]);
        async16(Bg + ko + 16384, &Blds[buf][w * 32 + 16][0]);
    };

    stage(0, 0);
    __syncthreads();

    for (int kt = 0; kt < 32; ++kt) {
        const int cur = kt & 1;
        if (kt + 1 < 32) stage(kt + 1, cur ^ 1);

        const u16 (*Lm)[32] = ktype ? Blds[cur] : Alds[cur];
        const u16 (*Ln)[32] = ktype ? Alds[cur] : Blds[cur];

        bf16x8 af[4], bf[4];
#pragma unroll
        for (int mt = 0; mt < 4; ++mt)
            af[mt] = *(const bf16x8*)&Lm[wm * 64 + mt * 16 + lc][(lr4 ^ sw) * 8];
#pragma unroll
        for (int nt = 0; nt < 4; ++nt)
            bf[nt] = *(const bf16x8*)&Ln[wn * 64 + nt * 16 + lc][(lr4 ^ sw) * 8];
#pragma unroll
        for (int mt = 0; mt < 4; ++mt)
#pragma unroll
            for (int nt = 0; nt < 4; ++nt)
                acc[mt][nt] = MFMA_BF16(af[mt], bf[nt], acc[mt][nt]);

        __syncthreads();
    }

    if (ktype) {
        // C^T: m = features, n = tokens. Lane holds 4 consecutive d.
#pragma unroll
        for (int mt = 0; mt < 4; ++mt)
#pragma unroll
            for (int nt = 0; nt < 4; ++nt) {
                int f   = colBase + wm * 64 + mt * 16 + lr4 * 4;
                int tok = rowBase + wn * 64 + nt * 16 + lc;
                int b = tok >> 10, tk = tok & 1023;
                int head = (f >> 6) & 15, d = f & 63;
                u16x4 pv = {f2bf(acc[mt][nt][0] * osc), f2bf(acc[mt][nt][1] * osc),
                            f2bf(acc[mt][nt][2] * osc), f2bf(acc[mt][nt][3] * osc)};
                *(u16x4*)&dK[((size_t)(b * 16 + head) * 1024 + tk) * 64 + d] = pv;
            }
    } else {
        // C: m = tokens, n = features. Transposed V store [B,16,64,L],
        // token index pi-permuted within each 32-block (4-aligned groups).
#pragma unroll
        for (int mt = 0; mt < 4; ++mt)
#pragma unroll
            for (int nt = 0; nt < 4; ++nt) {
                int gr0 = rowBase + wm * 64 + mt * 16 + lr4 * 4;
                int gc0 = colBase + wn * 64 + nt * 16;
                int head = gc0 >> 6;            // 16..31
                int b = gr0 >> 10, tok = gr0 & 1023;
                int tokp = (tok & ~31) | (((tok >> 2) & 3) << 3) |
                           (((tok >> 4) & 1) << 2);
                int d = (gc0 & 63) + lc;
                u16x4 pv = {f2bf(acc[mt][nt][0]), f2bf(acc[mt][nt][1]),
                            f2bf(acc[mt][nt][2]), f2bf(acc[mt][nt][3])};
                *(u16x4*)&dV[((size_t)(b * 16 + head - 16) * 64 + d) * 1024 +
                             tokp] = pv;
            }
    }
}

// ---------------------------------------------------------------------------
// Output GEMM: fp32 C = attn_bf16 x Wo^T, computed as C^T (A=Wo, B=attn).
// 64-token x 128-feature tiles -> 512 blocks (2/CU). float4 stores.
// XCD swizzle kept here: A(attn, 8MB) is the big re-use operand; row-chunking
// per XCD shrinks its re-fetch (Wo is only 2MB, fits any L2).
// ---------------------------------------------------------------------------
__global__ __launch_bounds__(256) void gemm_out(
    const u16* __restrict__ Aattn, const u16* __restrict__ Bwot,
    float* __restrict__ dst)
{
    __shared__ u16 Alds[64][32];    // tokens x k
    __shared__ u16 Blds[128][32];   // features x k
    const int t = threadIdx.x;
    const int l = t & 63, w = t >> 6;
    const int wm = w & 1, wn = w >> 1;          // wm: feature half, wn: token half

    const int wg  = blockIdx.y * 8 + blockIdx.x;   // 512 blocks
    const int swz = (wg & 7) * 64 + (wg >> 3);
    const int rowBase = (swz >> 3) * 64;        // tokens
    const int colBase = (swz & 7) * 128;        // features

    const int lc = l & 15, lr4 = l >> 4;

    f32x4 acc[4][2];
#pragma unroll
    for (int i = 0; i < 4; i++)
#pragma unroll
        for (int j = 0; j < 2; j++) acc[i][j] = (f32x4){0.f, 0.f, 0.f, 0.f};

    const int sl  = l >> 2;
    const int sc8 = (((l & 3) ^ (sl & 3)) * 8);
    const u16* Ag = Aattn + (size_t)(rowBase + w * 16 + sl) * 1024 + sc8;
    const u16* Bg = Bwot  + (size_t)(colBase + w * 32 + sl) * 1024 + sc8;
    const int sw = (lc & 3);

    for (int kt = 0; kt < 32; ++kt) {
        __syncthreads();
        const int ko = kt * 32;
        async16(Ag + ko,         &Alds[w * 16][0]);
        async16(Bg + ko,         &Blds[w * 32][0]);
        async16(Bg + ko + 16384, &Blds[w * 32 + 16][0]);
        __syncthreads();

        bf16x8 af[4], bf[2];
#pragma unroll
        for (int mt = 0; mt < 4; ++mt)
            af[mt] = *(const bf16x8*)&Blds[wm * 64 + mt * 16 + lc][(lr4 ^ sw) * 8];
#pragma unroll
        for (int nt = 0; nt < 2; ++nt)
            bf[nt] = *(const bf16x8*)&Alds[wn * 32 + nt * 16 + lc][(lr4 ^ sw) * 8];
#pragma unroll
        for (int mt = 0; mt < 4; ++mt)
#pragma unroll
            for (int nt = 0; nt < 2; ++nt)
                acc[mt][nt] = MFMA_BF16(af[mt], bf[nt], acc[mt][nt]);
    }

#pragma unroll
    for (int mt = 0; mt < 4; ++mt)
#pragma unroll
        for (int nt = 0; nt < 2; ++nt) {
            int f   = colBase + wm * 64 + mt * 16 + lr4 * 4;
            int tok = rowBase + wn * 32 + nt * 16 + lc;
            float4 v = {acc[mt][nt][0], acc[mt][nt][1],
                        acc[mt][nt][2], acc[mt][nt][3]};
            *(float4*)&dst[(size_t)tok * 1024 + f] = v;
        }
}

// ---------------------------------------------------------------------------
// Flash attention, transposed-MFMA (S^T, O^T), one branch per block,
// K/V double-buffered prefetch, one barrier/iter. Raw v_exp_f32.
// Branch 0 skips k-tiles with |q-k| > ~450 (decay weight < 2^-32).
// Zero-shuffle PV (pack2 words ARE the PV B-fragment; V pi-permuted by
// producer). Decay folded into MFMA C-init. launch_bounds (256,4).
// ---------------------------------------------------------------------------
__global__ __launch_bounds__(256, 4) void attn_mfma(
    const u16* __restrict__ Q, const u16* __restrict__ Ksb,
    const u16* __restrict__ Vsb, const u16* __restrict__ Klb,
    const u16* __restrict__ Vlb, const float* __restrict__ decayf,
    u16* __restrict__ Os, u16* __restrict__ Ol)
{
    __shared__ __align__(16) u16 Kt[2][2][64][32];  // [buf][d-half][krow][32d]
    __shared__ __align__(16) u16 Vt[2][2][64][32];  // [buf][k-half][d][32krow]

    const int t = threadIdx.x;
    const int l = t & 63, w = t >> 6;
    const int lc = l & 15, lr4 = l >> 4;
    const int h = blockIdx.x, qt = blockIdx.y;
    const int b = blockIdx.z >> 1, branch = blockIdx.z & 1;
    const size_t bh = (size_t)(b * 16 + h);
    const int qbase = qt * 128;
    const u16* Qg = Q + bh * (1024 * 64);
    const u16* Kg = (branch ? Klb : Ksb) + bh * (1024 * 64);
    const u16* Vg = (branch ? Vlb : Vsb) + bh * (64 * 1024);
    u16* outp = branch ? Ol : Os;

    const int sl = l >> 2;
    const int sc = (((l & 3) ^ ((l >> 3) & 3)) * 8);
    const int swr = (lc >> 1) & 3;

    // branch-0 range: only k-tiles with |q - k| < ~450 matter
    int ktLo = 0, ktHi = 16;
    if (branch == 0) {
        ktLo = qt * 2 - 7; if (ktLo < 0) ktLo = 0;
        ktHi = qt * 2 + 9; if (ktHi > 16) ktHi = 16;
    }

    // ---- Q B-operand fragments straight from global ----
    bf16x8 aQ[2][2];
#pragma unroll
    for (int qg = 0; qg < 2; ++qg)
#pragma unroll
        for (int kh = 0; kh < 2; ++kh)
            aQ[qg][kh] = *(const bf16x8*)&Qg[
                (size_t)(qbase + w * 32 + qg * 16 + lc) * 64 + kh * 32 + lr4 * 8];

    auto stage = [&](int kt, int buf) {
#pragma unroll
        for (int i = 0; i < 4; i++) {
            int id = w * 4 + i;
            int kh = (id >> 2) & 1, ch = id & 3;
            if (id < 8)
                async16(Kg + (size_t)(kt * 64 + ch * 16 + sl) * 64 + kh * 32 + sc,
                        &Kt[buf][kh][ch * 16][0]);
            else
                async16(Vg + (size_t)(ch * 16 + sl) * 1024 + kt * 64 + kh * 32 + sc,
                        &Vt[buf][kh][ch * 16][0]);
        }
    };

    stage(ktLo, 0);
    __syncthreads();

    const float C2 = (1.0f - decayf[0]) * 1.44269504f;
    const float qf = (float)(qbase + w * 32 + lc);

    f32x4 sumv[2] = {(f32x4){0.f, 0.f, 0.f, 0.f}, (f32x4){0.f, 0.f, 0.f, 0.f}};
    f32x4 o[2][4];
#pragma unroll
    for (int qg = 0; qg < 2; ++qg)
#pragma unroll
        for (int dt = 0; dt < 4; ++dt) o[qg][dt] = (f32x4){0.f, 0.f, 0.f, 0.f};

    for (int kt = ktLo, it = 0; kt < ktHi; ++kt, ++it) {
        const int cur = it & 1;
        if (kt + 1 < ktHi) stage(kt + 1, cur ^ 1);

        bf16x8 ak[4][2];
#pragma unroll
        for (int nt = 0; nt < 4; ++nt) {
            ak[nt][0] = *(const bf16x8*)&Kt[cur][0][nt * 16 + lc][(lr4 ^ swr) * 8];
            ak[nt][1] = *(const bf16x8*)&Kt[cur][1][nt * 16 + lc][(lr4 ^ swr) * 8];
        }

        unsigned pw[2][8];
#pragma unroll
        for (int qg = 0; qg < 2; ++qg) {
            const float d0 = qf + (float)(qg * 16 - kt * 64 - lr4 * 4);
            f32x4 s[4];
#pragma unroll
            for (int nt = 0; nt < 4; ++nt) {
                if (branch == 0) {
                    float dd = d0 - (float)(nt * 16);
                    s[nt] = (f32x4){-fabsf(dd) * C2,
                                    -fabsf(dd - 1.0f) * C2,
                                    -fabsf(dd - 2.0f) * C2,
                                    -fabsf(dd - 3.0f) * C2};
                } else {
                    s[nt] = (f32x4){0.f, 0.f, 0.f, 0.f};
                }
                s[nt] = MFMA_BF16(ak[nt][0], aQ[qg][0], s[nt]);
                s[nt] = MFMA_BF16(ak[nt][1], aQ[qg][1], s[nt]);
            }
#pragma unroll
            for (int nt = 0; nt < 4; ++nt) {
                float p0 = __builtin_amdgcn_exp2f(s[nt][0]);
                float p1 = __builtin_amdgcn_exp2f(s[nt][1]);
                float p2 = __builtin_amdgcn_exp2f(s[nt][2]);
                float p3 = __builtin_amdgcn_exp2f(s[nt][3]);
                sumv[qg][0] += p0; sumv[qg][1] += p1;
                sumv[qg][2] += p2; sumv[qg][3] += p3;
                pw[qg][nt * 2]     = pack2(p0, p1);
                pw[qg][nt * 2 + 1] = pack2(p2, p3);
            }
        }

#pragma unroll
        for (int dt = 0; dt < 4; ++dt) {
            bf16x8 v0 = *(const bf16x8*)&Vt[cur][0][dt * 16 + lc][(lr4 ^ swr) * 8];
            bf16x8 v1 = *(const bf16x8*)&Vt[cur][1][dt * 16 + lc][(lr4 ^ swr) * 8];
#pragma unroll
            for (int qg = 0; qg < 2; ++qg) {
                bf16x8 pb0 = mk_frag(pw[qg][0], pw[qg][1], pw[qg][2], pw[qg][3]);
                bf16x8 pb1 = mk_frag(pw[qg][4], pw[qg][5], pw[qg][6], pw[qg][7]);
                o[qg][dt] = MFMA_BF16(v0, pb0, o[qg][dt]);
                o[qg][dt] = MFMA_BF16(v1, pb1, o[qg][dt]);
            }
        }

        __syncthreads();
    }

#pragma unroll
    for (int qg = 0; qg < 2; ++qg) {
        float s = (sumv[qg][0] + sumv[qg][1]) + (sumv[qg][2] + sumv[qg][3]);
        s += __shfl_xor(s, 16);
        s += __shfl_xor(s, 32);
        float inv = 1.0f / s;
        int qrow = qbase + w * 32 + qg * 16 + lc;
        u16* op = outp + ((size_t)(b * 1024) + qrow) * 1024 + h * 64;
#pragma unroll
        for (int dt = 0; dt < 4; ++dt) {
            uint2 w2 = {pack2(o[qg][dt][0] * inv, o[qg][dt][1] * inv),
                        pack2(o[qg][dt][2] * inv, o[qg][dt][3] * inv)};
            *(uint2*)&op[dt * 16 + lr4 * 4] = w2;
        }
    }
}

// ---------------------------------------------------------------------------
// Mix: attn = alpha*Os + (1-alpha)*Ol, elementwise bf16.
// ---------------------------------------------------------------------------
__global__ __launch_bounds__(256) void mix_kernel(
    const u16* __restrict__ Os, const u16* __restrict__ Ol,
    const float* __restrict__ mixw, u16* __restrict__ dst)
{
    const float a = 1.0f / (1.0f + __expf(-mixw[0]));
    int i = blockIdx.x * 256 + threadIdx.x;
    uint4 s = ((const uint4*)Os)[i];
    uint4 l = ((const uint4*)Ol)[i];
    unsigned su[4] = {s.x, s.y, s.z, s.w};
    unsigned lu[4] = {l.x, l.y, l.z, l.w};
    unsigned ou[4];
#pragma unroll
    for (int k = 0; k < 4; ++k) {
        float s0 = bf2f((u16)su[k]), s1 = bf2f((u16)(su[k] >> 16));
        float l0 = bf2f((u16)lu[k]), l1 = bf2f((u16)(lu[k] >> 16));
        ou[k] = pack2(l0 + a * (s0 - l0), l1 + a * (s1 - l1));
    }
    ((uint4*)dst)[i] = make_uint4(ou[0], ou[1], ou[2], ou[3]);
}

// ---------------------------------------------------------------------------
extern "C" void kernel_launch(void* const* d_in, const int* in_sizes, int n_in,
                              void* d_out, int out_size, void* d_ws, size_t ws_size,
                              hipStream_t stream) {
    const float* x      = (const float*)d_in[0];
    const float* Wq     = (const float*)d_in[1];
    const float* Wkvs   = (const float*)d_in[2];
    const float* Wkvl   = (const float*)d_in[3];
    const float* Wo     = (const float*)d_in[4];
    const float* mixw   = (const float*)d_in[5];
    const float* decayf = (const float*)d_in[6];

    const size_t M1 = 1024 * 1024;
    u16* ws    = (u16*)d_ws;
    u16* xb    = ws;               // 4M  (reused as Os after gemm_proj)
    u16* wqt   = xb + 4 * M1;      // 1M  (wqt..wkvlt reused as Ol)
    u16* wkvst = wqt + 1 * M1;     // 2M
    u16* wkvlt = wkvst + 2 * M1;   // 2M
    u16* wot   = wkvlt + 2 * M1;   // 1M
    u16* qb    = wot + 1 * M1;     // 4M
    u16* ksb   = qb + 4 * M1;      // 4M
    u16* vsb   = ksb + 4 * M1;     // 4M  ([B,16,64,L], pi-permuted tokens)
    u16* klb   = vsb + 4 * M1;     // 4M
    u16* vlb   = klb + 4 * M1;     // 4M  (same)
    u16* attnb = vlb + 4 * M1;     // 4M
    u16* osb   = xb;               // alias: free after gemm_proj
    u16* olb   = wqt;              // alias: free after gemm_proj

    cvt_x<<<4096, 256, 0, stream>>>(x, xb);
    cvt_w_all<<<dim3(192, 32), 256, 0, stream>>>(Wq, Wkvs, Wkvl, Wo,
                                                 wqt, wkvst, wkvlt, wot);
    gemm_proj<<<dim3(40, 32), 256, 0, stream>>>(xb, wqt, wkvst, wkvlt,
                                                qb, ksb, vsb, klb, vlb);
    attn_mfma<<<dim3(16, 8, 8), 256, 0, stream>>>(qb, ksb, vsb, klb, vlb,
                                                  decayf, osb, olb);
    mix_kernel<<<2048, 256, 0, stream>>>(osb, olb, mixw, attnb);
    gemm_out<<<dim3(8, 64), 256, 0, stream>>>(attnb, wot, (float*)d_out);
}

// Round 7
// 226.941 us; speedup vs baseline: 1.0500x; 1.0010x over previous
//
#include <hip/hip_runtime.h>
#include <hip/hip_bf16.h>
#include <math.h>
#include <stdint.h>

typedef unsigned short u16;
typedef __attribute__((ext_vector_type(8))) short bf16x8;
typedef __attribute__((ext_vector_type(4))) float f32x4;
typedef __attribute__((ext_vector_type(4))) unsigned short u16x4;
typedef __attribute__((ext_vector_type(4))) unsigned int uint32x4;

#define MFMA_BF16(A, B, C) __builtin_amdgcn_mfma_f32_16x16x32_bf16((A), (B), (C), 0, 0, 0)

__device__ __forceinline__ void async16(const void* g, const void* l) {
    __builtin_amdgcn_global_load_lds(
        (const __attribute__((address_space(1))) unsigned int*)(uintptr_t)g,
        (__attribute__((address_space(3))) unsigned int*)(uintptr_t)l, 16, 0, 0);
}

__device__ __forceinline__ u16 f2bf(float f) {
    unsigned u = __float_as_uint(f);
    u += 0x7fffu + ((u >> 16) & 1u);
    return (u16)(u >> 16);
}

__device__ __forceinline__ unsigned pack2(float a, float b) {
    __hip_bfloat162 h = __float22bfloat162_rn(float2{a, b});
    return *reinterpret_cast<unsigned*>(&h);
}

__device__ __forceinline__ float bf2f(u16 v) {
    unsigned u = ((unsigned)v) << 16;
    return __uint_as_float(u);
}

__device__ __forceinline__ bf16x8 mk_frag(unsigned w0, unsigned w1,
                                          unsigned w2, unsigned w3) {
    uint32x4 u = {w0, w1, w2, w3};
    return __builtin_bit_cast(bf16x8, u);
}

// ---------------------------------------------------------------------------
// Converters
// ---------------------------------------------------------------------------
__global__ __launch_bounds__(256) void cvt_x(const float* __restrict__ x,
                                             u16* __restrict__ xb) {
    int i = blockIdx.x * 256 + threadIdx.x;
    float4 v = ((const float4*)x)[i];
    u16x4 o = {f2bf(v.x), f2bf(v.y), f2bf(v.z), f2bf(v.w)};
    ((u16x4*)xb)[i] = o;
}

// All 4 weights fp32 [K=1024][N] -> bf16 [N][1024] in one launch.
__global__ __launch_bounds__(256) void cvt_w_all(
    const float* __restrict__ Wq, const float* __restrict__ Wks,
    const float* __restrict__ Wkl, const float* __restrict__ Wo,
    u16* __restrict__ wqt, u16* __restrict__ wkst,
    u16* __restrict__ wklt, u16* __restrict__ wot)
{
    __shared__ float tile[32][33];
    int x = blockIdx.x;
    const float* W; u16* Wt; int N, nb;
    if (x < 32)       { W = Wq;  Wt = wqt;  N = 1024; nb = x * 32; }
    else if (x < 96)  { W = Wks; Wt = wkst; N = 2048; nb = (x - 32) * 32; }
    else if (x < 160) { W = Wkl; Wt = wklt; N = 2048; nb = (x - 96) * 32; }
    else              { W = Wo;  Wt = wot;  N = 1024; nb = (x - 160) * 32; }
    int kb = blockIdx.y * 32;
    int t = threadIdx.x;
    int r = t >> 3, c4 = (t & 7) * 4;
    float4 v = *(const float4*)&W[(size_t)(kb + r) * N + nb + c4];
    tile[r][c4] = v.x; tile[r][c4 + 1] = v.y;
    tile[r][c4 + 2] = v.z; tile[r][c4 + 3] = v.w;
    __syncthreads();
    u16x4 o = {f2bf(tile[c4 + 0][r]), f2bf(tile[c4 + 1][r]),
               f2bf(tile[c4 + 2][r]), f2bf(tile[c4 + 3][r])};
    *(u16x4*)&Wt[(size_t)(nb + r) * 1024 + kb + c4] = o;
}

// ---------------------------------------------------------------------------
// Fused projection GEMM. Q pre-scaled by 0.125*log2(e).
// R6: natural dispatch order (col-panel pinned to XCD -> weights L2-hot,
// FETCH 44 MB). 128x128 tile, acc 4x4, 2-deep prefetch dbuf (stage kt+1
// before compute kt, one barrier/step).
// R7: launch_bounds (256,3) -> (256,4). Unified regs = 52 arch (~56 aligned)
// + 64 AGPR = ~120 <= 128 budget -> 4 waves/SIMD fits without spill; the
// 4th co-resident block/CU adds drain overlap in this latency-bound loop.
// K-type tiles compute C^T -> u16x4 head-major stores. V-type compute C ->
// u16x4 transposed [B,16,64,L] stores, token pi-permuted within 32-blocks
// so attn's PV B-fragment needs no cross-lane shuffle.
// ---------------------------------------------------------------------------
__global__ __launch_bounds__(256, 4) void gemm_proj(
    const u16* __restrict__ A, const u16* __restrict__ wq,
    const u16* __restrict__ wks, const u16* __restrict__ wkl,
    u16* __restrict__ qd, u16* __restrict__ ksd, u16* __restrict__ vsd,
    u16* __restrict__ kld, u16* __restrict__ vld)
{
    __shared__ u16 Alds[2][128][32];   // x rows (tokens)     16 KB
    __shared__ u16 Blds[2][128][32];   // W rows (features)   16 KB

    const int cx = blockIdx.x;
    const int rowBase = blockIdx.y * 128;

    const u16* Bt; u16* dK; u16* dV; int colBase; float osc = 1.0f;
    bool ktype;
    if (cx < 8)       { Bt = wq;  colBase = cx * 128;        dK = qd;  dV = nullptr;
                        osc = 0.18033688f; ktype = true; }
    else if (cx < 24) { Bt = wks; colBase = (cx - 8) * 128;  dK = ksd; dV = vsd;
                        ktype = (cx < 16); }
    else              { Bt = wkl; colBase = (cx - 24) * 128; dK = kld; dV = vld;
                        ktype = (cx < 32); }

    const int t = threadIdx.x;
    const int l = t & 63, w = t >> 6;
    const int wm = w & 1, wn = w >> 1;
    const int lc = l & 15, lr4 = l >> 4;

    f32x4 acc[4][4];
#pragma unroll
    for (int i = 0; i < 4; i++)
#pragma unroll
        for (int j = 0; j < 4; j++) acc[i][j] = (f32x4){0.f, 0.f, 0.f, 0.f};

    const int srow = w * 32 + (l >> 2);
    const int sc8  = (((l & 3) ^ ((l >> 2) & 3)) * 8);
    const u16* Ag = A  + (size_t)(rowBase + srow) * 1024 + sc8;
    const u16* Bg = Bt + (size_t)(colBase + srow) * 1024 + sc8;
    const int sw = (lc & 3);

    auto stage = [&](int kt, int buf) {
        const int ko = kt * 32;
        async16(Ag + ko,         &Alds[buf][w * 32][0]);
        async16(Ag + ko + 16384, &Alds[buf][w * 32 + 16][0]);
        async16(Bg + ko,         &Blds[buf][w * 32][0]);
        async16(Bg + ko + 16384, &Blds[buf][w * 32 + 16][0]);
    };

    stage(0, 0);
    __syncthreads();

    for (int kt = 0; kt < 32; ++kt) {
        const int cur = kt & 1;
        if (kt + 1 < 32) stage(kt + 1, cur ^ 1);

        const u16 (*Lm)[32] = ktype ? Blds[cur] : Alds[cur];
        const u16 (*Ln)[32] = ktype ? Alds[cur] : Blds[cur];

        bf16x8 af[4], bf[4];
#pragma unroll
        for (int mt = 0; mt < 4; ++mt)
            af[mt] = *(const bf16x8*)&Lm[wm * 64 + mt * 16 + lc][(lr4 ^ sw) * 8];
#pragma unroll
        for (int nt = 0; nt < 4; ++nt)
            bf[nt] = *(const bf16x8*)&Ln[wn * 64 + nt * 16 + lc][(lr4 ^ sw) * 8];
#pragma unroll
        for (int mt = 0; mt < 4; ++mt)
#pragma unroll
            for (int nt = 0; nt < 4; ++nt)
                acc[mt][nt] = MFMA_BF16(af[mt], bf[nt], acc[mt][nt]);

        __syncthreads();
    }

    if (ktype) {
        // C^T: m = features, n = tokens. Lane holds 4 consecutive d.
#pragma unroll
        for (int mt = 0; mt < 4; ++mt)
#pragma unroll
            for (int nt = 0; nt < 4; ++nt) {
                int f   = colBase + wm * 64 + mt * 16 + lr4 * 4;
                int tok = rowBase + wn * 64 + nt * 16 + lc;
                int b = tok >> 10, tk = tok & 1023;
                int head = (f >> 6) & 15, d = f & 63;
                u16x4 pv = {f2bf(acc[mt][nt][0] * osc), f2bf(acc[mt][nt][1] * osc),
                            f2bf(acc[mt][nt][2] * osc), f2bf(acc[mt][nt][3] * osc)};
                *(u16x4*)&dK[((size_t)(b * 16 + head) * 1024 + tk) * 64 + d] = pv;
            }
    } else {
        // C: m = tokens, n = features. Transposed V store [B,16,64,L],
        // token index pi-permuted within each 32-block (4-aligned groups).
#pragma unroll
        for (int mt = 0; mt < 4; ++mt)
#pragma unroll
            for (int nt = 0; nt < 4; ++nt) {
                int gr0 = rowBase + wm * 64 + mt * 16 + lr4 * 4;
                int gc0 = colBase + wn * 64 + nt * 16;
                int head = gc0 >> 6;            // 16..31
                int b = gr0 >> 10, tok = gr0 & 1023;
                int tokp = (tok & ~31) | (((tok >> 2) & 3) << 3) |
                           (((tok >> 4) & 1) << 2);
                int d = (gc0 & 63) + lc;
                u16x4 pv = {f2bf(acc[mt][nt][0]), f2bf(acc[mt][nt][1]),
                            f2bf(acc[mt][nt][2]), f2bf(acc[mt][nt][3])};
                *(u16x4*)&dV[((size_t)(b * 16 + head - 16) * 64 + d) * 1024 +
                             tokp] = pv;
            }
    }
}

// ---------------------------------------------------------------------------
// Output GEMM: fp32 C = attn_bf16 x Wo^T, computed as C^T (A=Wo, B=attn).
// 64-token x 128-feature tiles -> 512 blocks (2/CU). float4 stores.
// XCD swizzle kept (A/attn 8MB is the re-use operand; row-chunk per XCD).
// R7: 2-deep prefetch double-buffer (was stage -> drain -> compute, which
// exposed full load latency every K-step). LDS 24 -> 48 KB.
// ---------------------------------------------------------------------------
__global__ __launch_bounds__(256) void gemm_out(
    const u16* __restrict__ Aattn, const u16* __restrict__ Bwot,
    float* __restrict__ dst)
{
    __shared__ u16 Alds[2][64][32];    // tokens x k     8 KB
    __shared__ u16 Blds[2][128][32];   // features x k  16 KB
    const int t = threadIdx.x;
    const int l = t & 63, w = t >> 6;
    const int wm = w & 1, wn = w >> 1;          // wm: feature half, wn: token half

    const int wg  = blockIdx.y * 8 + blockIdx.x;   // 512 blocks
    const int swz = (wg & 7) * 64 + (wg >> 3);
    const int rowBase = (swz >> 3) * 64;        // tokens
    const int colBase = (swz & 7) * 128;        // features

    const int lc = l & 15, lr4 = l >> 4;

    f32x4 acc[4][2];
#pragma unroll
    for (int i = 0; i < 4; i++)
#pragma unroll
        for (int j = 0; j < 2; j++) acc[i][j] = (f32x4){0.f, 0.f, 0.f, 0.f};

    const int sl  = l >> 2;
    const int sc8 = (((l & 3) ^ (sl & 3)) * 8);
    const u16* Ag = Aattn + (size_t)(rowBase + w * 16 + sl) * 1024 + sc8;
    const u16* Bg = Bwot  + (size_t)(colBase + w * 32 + sl) * 1024 + sc8;
    const int sw = (lc & 3);

    auto stage = [&](int kt, int buf) {
        const int ko = kt * 32;
        async16(Ag + ko,         &Alds[buf][w * 16][0]);
        async16(Bg + ko,         &Blds[buf][w * 32][0]);
        async16(Bg + ko + 16384, &Blds[buf][w * 32 + 16][0]);
    };

    stage(0, 0);
    __syncthreads();

    for (int kt = 0; kt < 32; ++kt) {
        const int cur = kt & 1;
        if (kt + 1 < 32) stage(kt + 1, cur ^ 1);

        bf16x8 af[4], bf[2];
#pragma unroll
        for (int mt = 0; mt < 4; ++mt)
            af[mt] = *(const bf16x8*)&Blds[cur][wm * 64 + mt * 16 + lc][(lr4 ^ sw) * 8];
#pragma unroll
        for (int nt = 0; nt < 2; ++nt)
            bf[nt] = *(const bf16x8*)&Alds[cur][wn * 32 + nt * 16 + lc][(lr4 ^ sw) * 8];
#pragma unroll
        for (int mt = 0; mt < 4; ++mt)
#pragma unroll
            for (int nt = 0; nt < 2; ++nt)
                acc[mt][nt] = MFMA_BF16(af[mt], bf[nt], acc[mt][nt]);

        __syncthreads();
    }

#pragma unroll
    for (int mt = 0; mt < 4; ++mt)
#pragma unroll
        for (int nt = 0; nt < 2; ++nt) {
            int f   = colBase + wm * 64 + mt * 16 + lr4 * 4;
            int tok = rowBase + wn * 32 + nt * 16 + lc;
            float4 v = {acc[mt][nt][0], acc[mt][nt][1],
                        acc[mt][nt][2], acc[mt][nt][3]};
            *(float4*)&dst[(size_t)tok * 1024 + f] = v;
        }
}

// ---------------------------------------------------------------------------
// Flash attention, transposed-MFMA (S^T, O^T), one branch per block,
// K/V double-buffered prefetch, one barrier/iter. Raw v_exp_f32.
// Branch 0 skips k-tiles with |q-k| > ~450 (decay weight < 2^-32).
// Zero-shuffle PV (pack2 words ARE the PV B-fragment; V pi-permuted by
// producer). Decay folded into MFMA C-init. launch_bounds (256,4).
// ---------------------------------------------------------------------------
__global__ __launch_bounds__(256, 4) void attn_mfma(
    const u16* __restrict__ Q, const u16* __restrict__ Ksb,
    const u16* __restrict__ Vsb, const u16* __restrict__ Klb,
    const u16* __restrict__ Vlb, const float* __restrict__ decayf,
    u16* __restrict__ Os, u16* __restrict__ Ol)
{
    __shared__ __align__(16) u16 Kt[2][2][64][32];  // [buf][d-half][krow][32d]
    __shared__ __align__(16) u16 Vt[2][2][64][32];  // [buf][k-half][d][32krow]

    const int t = threadIdx.x;
    const int l = t & 63, w = t >> 6;
    const int lc = l & 15, lr4 = l >> 4;
    const int h = blockIdx.x, qt = blockIdx.y;
    const int b = blockIdx.z >> 1, branch = blockIdx.z & 1;
    const size_t bh = (size_t)(b * 16 + h);
    const int qbase = qt * 128;
    const u16* Qg = Q + bh * (1024 * 64);
    const u16* Kg = (branch ? Klb : Ksb) + bh * (1024 * 64);
    const u16* Vg = (branch ? Vlb : Vsb) + bh * (64 * 1024);
    u16* outp = branch ? Ol : Os;

    const int sl = l >> 2;
    const int sc = (((l & 3) ^ ((l >> 3) & 3)) * 8);
    const int swr = (lc >> 1) & 3;

    // branch-0 range: only k-tiles with |q - k| < ~450 matter
    int ktLo = 0, ktHi = 16;
    if (branch == 0) {
        ktLo = qt * 2 - 7; if (ktLo < 0) ktLo = 0;
        ktHi = qt * 2 + 9; if (ktHi > 16) ktHi = 16;
    }

    // ---- Q B-operand fragments straight from global ----
    bf16x8 aQ[2][2];
#pragma unroll
    for (int qg = 0; qg < 2; ++qg)
#pragma unroll
        for (int kh = 0; kh < 2; ++kh)
            aQ[qg][kh] = *(const bf16x8*)&Qg[
                (size_t)(qbase + w * 32 + qg * 16 + lc) * 64 + kh * 32 + lr4 * 8];

    auto stage = [&](int kt, int buf) {
#pragma unroll
        for (int i = 0; i < 4; i++) {
            int id = w * 4 + i;
            int kh = (id >> 2) & 1, ch = id & 3;
            if (id < 8)
                async16(Kg + (size_t)(kt * 64 + ch * 16 + sl) * 64 + kh * 32 + sc,
                        &Kt[buf][kh][ch * 16][0]);
            else
                async16(Vg + (size_t)(ch * 16 + sl) * 1024 + kt * 64 + kh * 32 + sc,
                        &Vt[buf][kh][ch * 16][0]);
        }
    };

    stage(ktLo, 0);
    __syncthreads();

    const float C2 = (1.0f - decayf[0]) * 1.44269504f;
    const float qf = (float)(qbase + w * 32 + lc);

    f32x4 sumv[2] = {(f32x4){0.f, 0.f, 0.f, 0.f}, (f32x4){0.f, 0.f, 0.f, 0.f}};
    f32x4 o[2][4];
#pragma unroll
    for (int qg = 0; qg < 2; ++qg)
#pragma unroll
        for (int dt = 0; dt < 4; ++dt) o[qg][dt] = (f32x4){0.f, 0.f, 0.f, 0.f};

    for (int kt = ktLo, it = 0; kt < ktHi; ++kt, ++it) {
        const int cur = it & 1;
        if (kt + 1 < ktHi) stage(kt + 1, cur ^ 1);

        bf16x8 ak[4][2];
#pragma unroll
        for (int nt = 0; nt < 4; ++nt) {
            ak[nt][0] = *(const bf16x8*)&Kt[cur][0][nt * 16 + lc][(lr4 ^ swr) * 8];
            ak[nt][1] = *(const bf16x8*)&Kt[cur][1][nt * 16 + lc][(lr4 ^ swr) * 8];
        }

        unsigned pw[2][8];
#pragma unroll
        for (int qg = 0; qg < 2; ++qg) {
            const float d0 = qf + (float)(qg * 16 - kt * 64 - lr4 * 4);
            f32x4 s[4];
#pragma unroll
            for (int nt = 0; nt < 4; ++nt) {
                if (branch == 0) {
                    float dd = d0 - (float)(nt * 16);
                    s[nt] = (f32x4){-fabsf(dd) * C2,
                                    -fabsf(dd - 1.0f) * C2,
                                    -fabsf(dd - 2.0f) * C2,
                                    -fabsf(dd - 3.0f) * C2};
                } else {
                    s[nt] = (f32x4){0.f, 0.f, 0.f, 0.f};
                }
                s[nt] = MFMA_BF16(ak[nt][0], aQ[qg][0], s[nt]);
                s[nt] = MFMA_BF16(ak[nt][1], aQ[qg][1], s[nt]);
            }
#pragma unroll
            for (int nt = 0; nt < 4; ++nt) {
                float p0 = __builtin_amdgcn_exp2f(s[nt][0]);
                float p1 = __builtin_amdgcn_exp2f(s[nt][1]);
                float p2 = __builtin_amdgcn_exp2f(s[nt][2]);
                float p3 = __builtin_amdgcn_exp2f(s[nt][3]);
                sumv[qg][0] += p0; sumv[qg][1] += p1;
                sumv[qg][2] += p2; sumv[qg][3] += p3;
                pw[qg][nt * 2]     = pack2(p0, p1);
                pw[qg][nt * 2 + 1] = pack2(p2, p3);
            }
        }

#pragma unroll
        for (int dt = 0; dt < 4; ++dt) {
            bf16x8 v0 = *(const bf16x8*)&Vt[cur][0][dt * 16 + lc][(lr4 ^ swr) * 8];
            bf16x8 v1 = *(const bf16x8*)&Vt[cur][1][dt * 16 + lc][(lr4 ^ swr) * 8];
#pragma unroll
            for (int qg = 0; qg < 2; ++qg) {
                bf16x8 pb0 = mk_frag(pw[qg][0], pw[qg][1], pw[qg][2], pw[qg][3]);
                bf16x8 pb1 = mk_frag(pw[qg][4], pw[qg][5], pw[qg][6], pw[qg][7]);
                o[qg][dt] = MFMA_BF16(v0, pb0, o[qg][dt]);
                o[qg][dt] = MFMA_BF16(v1, pb1, o[qg][dt]);
            }
        }

        __syncthreads();
    }

#pragma unroll
    for (int qg = 0; qg < 2; ++qg) {
        float s = (sumv[qg][0] + sumv[qg][1]) + (sumv[qg][2] + sumv[qg][3]);
        s += __shfl_xor(s, 16);
        s += __shfl_xor(s, 32);
        float inv = 1.0f / s;
        int qrow = qbase + w * 32 + qg * 16 + lc;
        u16* op = outp + ((size_t)(b * 1024) + qrow) * 1024 + h * 64;
#pragma unroll
        for (int dt = 0; dt < 4; ++dt) {
            uint2 w2 = {pack2(o[qg][dt][0] * inv, o[qg][dt][1] * inv),
                        pack2(o[qg][dt][2] * inv, o[qg][dt][3] * inv)};
            *(uint2*)&op[dt * 16 + lr4 * 4] = w2;
        }
    }
}

// ---------------------------------------------------------------------------
// Mix: attn = alpha*Os + (1-alpha)*Ol, elementwise bf16.
// ---------------------------------------------------------------------------
__global__ __launch_bounds__(256) void mix_kernel(
    const u16* __restrict__ Os, const u16* __restrict__ Ol,
    const float* __restrict__ mixw, u16* __restrict__ dst)
{
    const float a = 1.0f / (1.0f + __expf(-mixw[0]));
    int i = blockIdx.x * 256 + threadIdx.x;
    uint4 s = ((const uint4*)Os)[i];
    uint4 l = ((const uint4*)Ol)[i];
    unsigned su[4] = {s.x, s.y, s.z, s.w};
    unsigned lu[4] = {l.x, l.y, l.z, l.w};
    unsigned ou[4];
#pragma unroll
    for (int k = 0; k < 4; ++k) {
        float s0 = bf2f((u16)su[k]), s1 = bf2f((u16)(su[k] >> 16));
        float l0 = bf2f((u16)lu[k]), l1 = bf2f((u16)(lu[k] >> 16));
        ou[k] = pack2(l0 + a * (s0 - l0), l1 + a * (s1 - l1));
    }
    ((uint4*)dst)[i] = make_uint4(ou[0], ou[1], ou[2], ou[3]);
}

// ---------------------------------------------------------------------------
extern "C" void kernel_launch(void* const* d_in, const int* in_sizes, int n_in,
                              void* d_out, int out_size, void* d_ws, size_t ws_size,
                              hipStream_t stream) {
    const float* x      = (const float*)d_in[0];
    const float* Wq     = (const float*)d_in[1];
    const float* Wkvs   = (const float*)d_in[2];
    const float* Wkvl   = (const float*)d_in[3];
    const float* Wo     = (const float*)d_in[4];
    const float* mixw   = (const float*)d_in[5];
    const float* decayf = (const float*)d_in[6];

    const size_t M1 = 1024 * 1024;
    u16* ws    = (u16*)d_ws;
    u16* xb    = ws;               // 4M  (reused as Os after gemm_proj)
    u16* wqt   = xb + 4 * M1;      // 1M  (wqt..wkvlt reused as Ol)
    u16* wkvst = wqt + 1 * M1;     // 2M
    u16* wkvlt = wkvst + 2 * M1;   // 2M
    u16* wot   = wkvlt + 2 * M1;   // 1M
    u16* qb    = wot + 1 * M1;     // 4M
    u16* ksb   = qb + 4 * M1;      // 4M
    u16* vsb   = ksb + 4 * M1;     // 4M  ([B,16,64,L], pi-permuted tokens)
    u16* klb   = vsb + 4 * M1;     // 4M
    u16* vlb   = klb + 4 * M1;     // 4M  (same)
    u16* attnb = vlb + 4 * M1;     // 4M
    u16* osb   = xb;               // alias: free after gemm_proj
    u16* olb   = wqt;              // alias: free after gemm_proj

    cvt_x<<<4096, 256, 0, stream>>>(x, xb);
    cvt_w_all<<<dim3(192, 32), 256, 0, stream>>>(Wq, Wkvs, Wkvl, Wo,
                                                 wqt, wkvst, wkvlt, wot);
    gemm_proj<<<dim3(40, 32), 256, 0, stream>>>(xb, wqt, wkvst, wkvlt,
                                                qb, ksb, vsb, klb, vlb);
    attn_mfma<<<dim3(16, 8, 8), 256, 0, stream>>>(qb, ksb, vsb, klb, vlb,
                                                  decayf, osb, olb);
    mix_kernel<<<2048, 256, 0, stream>>>(osb, olb, mixw, attnb);
    gemm_out<<<dim3(8, 64), 256, 0, stream>>>(attnb, wot, (float*)d_out);
}

// Round 8
// 218.732 us; speedup vs baseline: 1.0894x; 1.0375x over previous
//
#include <hip/hip_runtime.h>
#include <hip/hip_bf16.h>
#include <math.h>
#include <stdint.h>

typedef unsigned short u16;
typedef __attribute__((ext_vector_type(8))) short bf16x8;
typedef __attribute__((ext_vector_type(4))) float f32x4;
typedef __attribute__((ext_vector_type(4))) unsigned short u16x4;
typedef __attribute__((ext_vector_type(4))) unsigned int uint32x4;

#define MFMA_BF16(A, B, C) __builtin_amdgcn_mfma_f32_16x16x32_bf16((A), (B), (C), 0, 0, 0)

__device__ __forceinline__ void async16(const void* g, const void* l) {
    __builtin_amdgcn_global_load_lds(
        (const __attribute__((address_space(1))) unsigned int*)(uintptr_t)g,
        (__attribute__((address_space(3))) unsigned int*)(uintptr_t)l, 16, 0, 0);
}

__device__ __forceinline__ u16 f2bf(float f) {
    unsigned u = __float_as_uint(f);
    u += 0x7fffu + ((u >> 16) & 1u);
    return (u16)(u >> 16);
}

__device__ __forceinline__ unsigned pack2(float a, float b) {
    __hip_bfloat162 h = __float22bfloat162_rn(float2{a, b});
    return *reinterpret_cast<unsigned*>(&h);
}

__device__ __forceinline__ float bf2f(u16 v) {
    unsigned u = ((unsigned)v) << 16;
    return __uint_as_float(u);
}

__device__ __forceinline__ bf16x8 mk_frag(unsigned w0, unsigned w1,
                                          unsigned w2, unsigned w3) {
    uint32x4 u = {w0, w1, w2, w3};
    return __builtin_bit_cast(bf16x8, u);
}

// ---------------------------------------------------------------------------
// Converters
// ---------------------------------------------------------------------------
__global__ __launch_bounds__(256) void cvt_x(const float* __restrict__ x,
                                             u16* __restrict__ xb) {
    int i = blockIdx.x * 256 + threadIdx.x;
    float4 v = ((const float4*)x)[i];
    u16x4 o = {f2bf(v.x), f2bf(v.y), f2bf(v.z), f2bf(v.w)};
    ((u16x4*)xb)[i] = o;
}

// All 4 weights fp32 [K=1024][N] -> bf16 [N][1024] in one launch.
__global__ __launch_bounds__(256) void cvt_w_all(
    const float* __restrict__ Wq, const float* __restrict__ Wks,
    const float* __restrict__ Wkl, const float* __restrict__ Wo,
    u16* __restrict__ wqt, u16* __restrict__ wkst,
    u16* __restrict__ wklt, u16* __restrict__ wot)
{
    __shared__ float tile[32][33];
    int x = blockIdx.x;
    const float* W; u16* Wt; int N, nb;
    if (x < 32)       { W = Wq;  Wt = wqt;  N = 1024; nb = x * 32; }
    else if (x < 96)  { W = Wks; Wt = wkst; N = 2048; nb = (x - 32) * 32; }
    else if (x < 160) { W = Wkl; Wt = wklt; N = 2048; nb = (x - 96) * 32; }
    else              { W = Wo;  Wt = wot;  N = 1024; nb = (x - 160) * 32; }
    int kb = blockIdx.y * 32;
    int t = threadIdx.x;
    int r = t >> 3, c4 = (t & 7) * 4;
    float4 v = *(const float4*)&W[(size_t)(kb + r) * N + nb + c4];
    tile[r][c4] = v.x; tile[r][c4 + 1] = v.y;
    tile[r][c4 + 2] = v.z; tile[r][c4 + 3] = v.w;
    __syncthreads();
    u16x4 o = {f2bf(tile[c4 + 0][r]), f2bf(tile[c4 + 1][r]),
               f2bf(tile[c4 + 2][r]), f2bf(tile[c4 + 3][r])};
    *(u16x4*)&Wt[(size_t)(nb + r) * 1024 + kb + c4] = o;
}

// ---------------------------------------------------------------------------
// Fused projection GEMM. Q pre-scaled by 0.125*log2(e).
// Natural dispatch order (col-panel pinned to XCD -> weights L2-hot).
// 128x128 tile, acc 4x4, 2-deep prefetch dbuf, one barrier/step.
// K-type tiles compute C^T -> u16x4 head-major stores. V-type compute C ->
// u16x4 transposed [B,16,64,L] stores, token pi-permuted within 32-blocks
// so attn's PV B-fragment needs no cross-lane shuffle.
// ---------------------------------------------------------------------------
__global__ __launch_bounds__(256, 4) void gemm_proj(
    const u16* __restrict__ A, const u16* __restrict__ wq,
    const u16* __restrict__ wks, const u16* __restrict__ wkl,
    u16* __restrict__ qd, u16* __restrict__ ksd, u16* __restrict__ vsd,
    u16* __restrict__ kld, u16* __restrict__ vld)
{
    __shared__ u16 Alds[2][128][32];   // x rows (tokens)     16 KB
    __shared__ u16 Blds[2][128][32];   // W rows (features)   16 KB

    const int cx = blockIdx.x;
    const int rowBase = blockIdx.y * 128;

    const u16* Bt; u16* dK; u16* dV; int colBase; float osc = 1.0f;
    bool ktype;
    if (cx < 8)       { Bt = wq;  colBase = cx * 128;        dK = qd;  dV = nullptr;
                        osc = 0.18033688f; ktype = true; }
    else if (cx < 24) { Bt = wks; colBase = (cx - 8) * 128;  dK = ksd; dV = vsd;
                        ktype = (cx < 16); }
    else              { Bt = wkl; colBase = (cx - 24) * 128; dK = kld; dV = vld;
                        ktype = (cx < 32); }

    const int t = threadIdx.x;
    const int l = t & 63, w = t >> 6;
    const int wm = w & 1, wn = w >> 1;
    const int lc = l & 15, lr4 = l >> 4;

    f32x4 acc[4][4];
#pragma unroll
    for (int i = 0; i < 4; i++)
#pragma unroll
        for (int j = 0; j < 4; j++) acc[i][j] = (f32x4){0.f, 0.f, 0.f, 0.f};

    const int srow = w * 32 + (l >> 2);
    const int sc8  = (((l & 3) ^ ((l >> 2) & 3)) * 8);
    const u16* Ag = A  + (size_t)(rowBase + srow) * 1024 + sc8;
    const u16* Bg = Bt + (size_t)(colBase + srow) * 1024 + sc8;
    const int sw = (lc & 3);

    auto stage = [&](int kt, int buf) {
        const int ko = kt * 32;
        async16(Ag + ko,         &Alds[buf][w * 32][0]);
        async16(Ag + ko + 16384, &Alds[buf][w * 32 + 16][0]);
        async16(Bg + ko,         &Blds[buf][w * 32][0]);
        async16(Bg + ko + 16384, &Blds[buf][w * 32 + 16][0]);
    };

    stage(0, 0);
    __syncthreads();

    for (int kt = 0; kt < 32; ++kt) {
        const int cur = kt & 1;
        if (kt + 1 < 32) stage(kt + 1, cur ^ 1);

        const u16 (*Lm)[32] = ktype ? Blds[cur] : Alds[cur];
        const u16 (*Ln)[32] = ktype ? Alds[cur] : Blds[cur];

        bf16x8 af[4], bf[4];
#pragma unroll
        for (int mt = 0; mt < 4; ++mt)
            af[mt] = *(const bf16x8*)&Lm[wm * 64 + mt * 16 + lc][(lr4 ^ sw) * 8];
#pragma unroll
        for (int nt = 0; nt < 4; ++nt)
            bf[nt] = *(const bf16x8*)&Ln[wn * 64 + nt * 16 + lc][(lr4 ^ sw) * 8];
#pragma unroll
        for (int mt = 0; mt < 4; ++mt)
#pragma unroll
            for (int nt = 0; nt < 4; ++nt)
                acc[mt][nt] = MFMA_BF16(af[mt], bf[nt], acc[mt][nt]);

        __syncthreads();
    }

    if (ktype) {
        // C^T: m = features, n = tokens. Lane holds 4 consecutive d.
#pragma unroll
        for (int mt = 0; mt < 4; ++mt)
#pragma unroll
            for (int nt = 0; nt < 4; ++nt) {
                int f   = colBase + wm * 64 + mt * 16 + lr4 * 4;
                int tok = rowBase + wn * 64 + nt * 16 + lc;
                int b = tok >> 10, tk = tok & 1023;
                int head = (f >> 6) & 15, d = f & 63;
                u16x4 pv = {f2bf(acc[mt][nt][0] * osc), f2bf(acc[mt][nt][1] * osc),
                            f2bf(acc[mt][nt][2] * osc), f2bf(acc[mt][nt][3] * osc)};
                *(u16x4*)&dK[((size_t)(b * 16 + head) * 1024 + tk) * 64 + d] = pv;
            }
    } else {
        // C: m = tokens, n = features. Transposed V store [B,16,64,L],
        // token index pi-permuted within each 32-block (4-aligned groups).
#pragma unroll
        for (int mt = 0; mt < 4; ++mt)
#pragma unroll
            for (int nt = 0; nt < 4; ++nt) {
                int gr0 = rowBase + wm * 64 + mt * 16 + lr4 * 4;
                int gc0 = colBase + wn * 64 + nt * 16;
                int head = gc0 >> 6;            // 16..31
                int b = gr0 >> 10, tok = gr0 & 1023;
                int tokp = (tok & ~31) | (((tok >> 2) & 3) << 3) |
                           (((tok >> 4) & 1) << 2);
                int d = (gc0 & 63) + lc;
                u16x4 pv = {f2bf(acc[mt][nt][0]), f2bf(acc[mt][nt][1]),
                            f2bf(acc[mt][nt][2]), f2bf(acc[mt][nt][3])};
                *(u16x4*)&dV[((size_t)(b * 16 + head - 16) * 64 + d) * 1024 +
                             tokp] = pv;
            }
    }
}

// ---------------------------------------------------------------------------
// Output GEMM: fp32 C = attn_bf16 x Wo^T, computed as C^T (A=Wo, B=attn).
// 64-token x 128-feature tiles -> 512 blocks (2/CU). float4 stores.
// XCD swizzle + 2-deep prefetch double-buffer.
// ---------------------------------------------------------------------------
__global__ __launch_bounds__(256) void gemm_out(
    const u16* __restrict__ Aattn, const u16* __restrict__ Bwot,
    float* __restrict__ dst)
{
    __shared__ u16 Alds[2][64][32];    // tokens x k     8 KB
    __shared__ u16 Blds[2][128][32];   // features x k  16 KB
    const int t = threadIdx.x;
    const int l = t & 63, w = t >> 6;
    const int wm = w & 1, wn = w >> 1;          // wm: feature half, wn: token half

    const int wg  = blockIdx.y * 8 + blockIdx.x;   // 512 blocks
    const int swz = (wg & 7) * 64 + (wg >> 3);
    const int rowBase = (swz >> 3) * 64;        // tokens
    const int colBase = (swz & 7) * 128;        // features

    const int lc = l & 15, lr4 = l >> 4;

    f32x4 acc[4][2];
#pragma unroll
    for (int i = 0; i < 4; i++)
#pragma unroll
        for (int j = 0; j < 2; j++) acc[i][j] = (f32x4){0.f, 0.f, 0.f, 0.f};

    const int sl  = l >> 2;
    const int sc8 = (((l & 3) ^ (sl & 3)) * 8);
    const u16* Ag = Aattn + (size_t)(rowBase + w * 16 + sl) * 1024 + sc8;
    const u16* Bg = Bwot  + (size_t)(colBase + w * 32 + sl) * 1024 + sc8;
    const int sw = (lc & 3);

    auto stage = [&](int kt, int buf) {
        const int ko = kt * 32;
        async16(Ag + ko,         &Alds[buf][w * 16][0]);
        async16(Bg + ko,         &Blds[buf][w * 32][0]);
        async16(Bg + ko + 16384, &Blds[buf][w * 32 + 16][0]);
    };

    stage(0, 0);
    __syncthreads();

    for (int kt = 0; kt < 32; ++kt) {
        const int cur = kt & 1;
        if (kt + 1 < 32) stage(kt + 1, cur ^ 1);

        bf16x8 af[4], bf[2];
#pragma unroll
        for (int mt = 0; mt < 4; ++mt)
            af[mt] = *(const bf16x8*)&Blds[cur][wm * 64 + mt * 16 + lc][(lr4 ^ sw) * 8];
#pragma unroll
        for (int nt = 0; nt < 2; ++nt)
            bf[nt] = *(const bf16x8*)&Alds[cur][wn * 32 + nt * 16 + lc][(lr4 ^ sw) * 8];
#pragma unroll
        for (int mt = 0; mt < 4; ++mt)
#pragma unroll
            for (int nt = 0; nt < 2; ++nt)
                acc[mt][nt] = MFMA_BF16(af[mt], bf[nt], acc[mt][nt]);

        __syncthreads();
    }

#pragma unroll
    for (int mt = 0; mt < 4; ++mt)
#pragma unroll
        for (int nt = 0; nt < 2; ++nt) {
            int f   = colBase + wm * 64 + mt * 16 + lr4 * 4;
            int tok = rowBase + wn * 32 + nt * 16 + lc;
            float4 v = {acc[mt][nt][0], acc[mt][nt][1],
                        acc[mt][nt][2], acc[mt][nt][3]};
            *(float4*)&dst[(size_t)tok * 1024 + f] = v;
        }
}

// ---------------------------------------------------------------------------
// Flash attention, transposed-MFMA (S^T, O^T), K/V double-buffered prefetch,
// one barrier/iter. Zero-shuffle PV (pack2 words ARE the PV B-fragment; V
// pi-permuted by producer). Decay folded into MFMA C-init.
//
// R8: BOTH branches fused in one block (sequential br loop over the same
// LDS buffers) + in-register mix -> mix_kernel deleted. Q fragments loaded
// once; branch-0 output normalized and packed to bf16 (16 VGPRs, numerics
// == old mix_kernel which also read bf16 Os); branch-1 epilogue computes
// l + alpha*(s - l) and writes final attnb directly. Saves 16MB write +
// 16MB read (Os/Ol round-trip) + 8MB Q re-read + one dispatch.
// Register peak ~145 -> launch_bounds(256,3) (170-reg cap, no spill).
// ---------------------------------------------------------------------------
__global__ __launch_bounds__(256, 3) void attn_mfma(
    const u16* __restrict__ Q, const u16* __restrict__ Ksb,
    const u16* __restrict__ Vsb, const u16* __restrict__ Klb,
    const u16* __restrict__ Vlb, const float* __restrict__ decayf,
    const float* __restrict__ mixw, u16* __restrict__ dst)
{
    __shared__ __align__(16) u16 Kt[2][2][64][32];  // [buf][d-half][krow][32d]
    __shared__ __align__(16) u16 Vt[2][2][64][32];  // [buf][k-half][d][32krow]

    const int t = threadIdx.x;
    const int l = t & 63, w = t >> 6;
    const int lc = l & 15, lr4 = l >> 4;
    const int h = blockIdx.x, qt = blockIdx.y, b = blockIdx.z;
    const size_t bh = (size_t)(b * 16 + h);
    const int qbase = qt * 128;
    const u16* Qg = Q + bh * (1024 * 64);

    const int sl = l >> 2;
    const int sc = (((l & 3) ^ ((l >> 3) & 3)) * 8);
    const int swr = (lc >> 1) & 3;

    // ---- Q B-operand fragments straight from global (shared by branches) --
    bf16x8 aQ[2][2];
#pragma unroll
    for (int qg = 0; qg < 2; ++qg)
#pragma unroll
        for (int kh = 0; kh < 2; ++kh)
            aQ[qg][kh] = *(const bf16x8*)&Qg[
                (size_t)(qbase + w * 32 + qg * 16 + lc) * 64 + kh * 32 + lr4 * 8];

    const float C2 = (1.0f - decayf[0]) * 1.44269504f;
    const float alpha = 1.0f / (1.0f + __expf(-mixw[0]));
    const float qf = (float)(qbase + w * 32 + lc);

    uint2 w0[2][4];  // branch-0 normalized output, bf16-packed

#pragma unroll
    for (int br = 0; br < 2; ++br) {
        const u16* Kg = (br ? Klb : Ksb) + bh * (1024 * 64);
        const u16* Vg = (br ? Vlb : Vsb) + bh * (64 * 1024);

        // branch-0 range: only k-tiles with |q - k| < ~450 matter
        int ktLo = 0, ktHi = 16;
        if (br == 0) {
            ktLo = qt * 2 - 7; if (ktLo < 0) ktLo = 0;
            ktHi = qt * 2 + 9; if (ktHi > 16) ktHi = 16;
        }

        auto stage = [&](int kt, int buf) {
#pragma unroll
            for (int i = 0; i < 4; i++) {
                int id = w * 4 + i;
                int kh = (id >> 2) & 1, ch = id & 3;
                if (id < 8)
                    async16(Kg + (size_t)(kt * 64 + ch * 16 + sl) * 64 + kh * 32 + sc,
                            &Kt[buf][kh][ch * 16][0]);
                else
                    async16(Vg + (size_t)(ch * 16 + sl) * 1024 + kt * 64 + kh * 32 + sc,
                            &Vt[buf][kh][ch * 16][0]);
            }
        };

        f32x4 sumv[2] = {(f32x4){0.f, 0.f, 0.f, 0.f},
                         (f32x4){0.f, 0.f, 0.f, 0.f}};
        f32x4 o[2][4];
#pragma unroll
        for (int qg = 0; qg < 2; ++qg)
#pragma unroll
            for (int dt = 0; dt < 4; ++dt) o[qg][dt] = (f32x4){0.f, 0.f, 0.f, 0.f};

        stage(ktLo, 0);
        __syncthreads();

        for (int kt = ktLo, it = 0; kt < ktHi; ++kt, ++it) {
            const int cur = it & 1;
            if (kt + 1 < ktHi) stage(kt + 1, cur ^ 1);

            bf16x8 ak[4][2];
#pragma unroll
            for (int nt = 0; nt < 4; ++nt) {
                ak[nt][0] = *(const bf16x8*)&Kt[cur][0][nt * 16 + lc][(lr4 ^ swr) * 8];
                ak[nt][1] = *(const bf16x8*)&Kt[cur][1][nt * 16 + lc][(lr4 ^ swr) * 8];
            }

            unsigned pw[2][8];
#pragma unroll
            for (int qg = 0; qg < 2; ++qg) {
                const float d0 = qf + (float)(qg * 16 - kt * 64 - lr4 * 4);
                f32x4 s[4];
#pragma unroll
                for (int nt = 0; nt < 4; ++nt) {
                    if (br == 0) {
                        float dd = d0 - (float)(nt * 16);
                        s[nt] = (f32x4){-fabsf(dd) * C2,
                                        -fabsf(dd - 1.0f) * C2,
                                        -fabsf(dd - 2.0f) * C2,
                                        -fabsf(dd - 3.0f) * C2};
                    } else {
                        s[nt] = (f32x4){0.f, 0.f, 0.f, 0.f};
                    }
                    s[nt] = MFMA_BF16(ak[nt][0], aQ[qg][0], s[nt]);
                    s[nt] = MFMA_BF16(ak[nt][1], aQ[qg][1], s[nt]);
                }
#pragma unroll
                for (int nt = 0; nt < 4; ++nt) {
                    float p0 = __builtin_amdgcn_exp2f(s[nt][0]);
                    float p1 = __builtin_amdgcn_exp2f(s[nt][1]);
                    float p2 = __builtin_amdgcn_exp2f(s[nt][2]);
                    float p3 = __builtin_amdgcn_exp2f(s[nt][3]);
                    sumv[qg][0] += p0; sumv[qg][1] += p1;
                    sumv[qg][2] += p2; sumv[qg][3] += p3;
                    pw[qg][nt * 2]     = pack2(p0, p1);
                    pw[qg][nt * 2 + 1] = pack2(p2, p3);
                }
            }

#pragma unroll
            for (int dt = 0; dt < 4; ++dt) {
                bf16x8 v0 = *(const bf16x8*)&Vt[cur][0][dt * 16 + lc][(lr4 ^ swr) * 8];
                bf16x8 v1 = *(const bf16x8*)&Vt[cur][1][dt * 16 + lc][(lr4 ^ swr) * 8];
#pragma unroll
                for (int qg = 0; qg < 2; ++qg) {
                    bf16x8 pb0 = mk_frag(pw[qg][0], pw[qg][1], pw[qg][2], pw[qg][3]);
                    bf16x8 pb1 = mk_frag(pw[qg][4], pw[qg][5], pw[qg][6], pw[qg][7]);
                    o[qg][dt] = MFMA_BF16(v0, pb0, o[qg][dt]);
                    o[qg][dt] = MFMA_BF16(v1, pb1, o[qg][dt]);
                }
            }

            __syncthreads();
        }

        // ---- normalize; br0 packs to bf16, br1 mixes and stores ----
#pragma unroll
        for (int qg = 0; qg < 2; ++qg) {
            float s = (sumv[qg][0] + sumv[qg][1]) + (sumv[qg][2] + sumv[qg][3]);
            s += __shfl_xor(s, 16);
            s += __shfl_xor(s, 32);
            float inv = 1.0f / s;
            if (br == 0) {
#pragma unroll
                for (int dt = 0; dt < 4; ++dt)
                    w0[qg][dt] = uint2{
                        pack2(o[qg][dt][0] * inv, o[qg][dt][1] * inv),
                        pack2(o[qg][dt][2] * inv, o[qg][dt][3] * inv)};
            } else {
                int qrow = qbase + w * 32 + qg * 16 + lc;
                u16* op = dst + ((size_t)(b * 1024) + qrow) * 1024 + h * 64;
#pragma unroll
                for (int dt = 0; dt < 4; ++dt) {
                    float s0 = bf2f((u16)(w0[qg][dt].x));
                    float s1 = bf2f((u16)(w0[qg][dt].x >> 16));
                    float s2 = bf2f((u16)(w0[qg][dt].y));
                    float s3 = bf2f((u16)(w0[qg][dt].y >> 16));
                    float l0 = o[qg][dt][0] * inv, l1 = o[qg][dt][1] * inv;
                    float l2 = o[qg][dt][2] * inv, l3 = o[qg][dt][3] * inv;
                    uint2 w2 = {pack2(l0 + alpha * (s0 - l0),
                                      l1 + alpha * (s1 - l1)),
                                pack2(l2 + alpha * (s2 - l2),
                                      l3 + alpha * (s3 - l3))};
                    *(uint2*)&op[dt * 16 + lr4 * 4] = w2;
                }
            }
        }
    }
}

// ---------------------------------------------------------------------------
extern "C" void kernel_launch(void* const* d_in, const int* in_sizes, int n_in,
                              void* d_out, int out_size, void* d_ws, size_t ws_size,
                              hipStream_t stream) {
    const float* x      = (const float*)d_in[0];
    const float* Wq     = (const float*)d_in[1];
    const float* Wkvs   = (const float*)d_in[2];
    const float* Wkvl   = (const float*)d_in[3];
    const float* Wo     = (const float*)d_in[4];
    const float* mixw   = (const float*)d_in[5];
    const float* decayf = (const float*)d_in[6];

    const size_t M1 = 1024 * 1024;
    u16* ws    = (u16*)d_ws;
    u16* xb    = ws;               // 4M
    u16* wqt   = xb + 4 * M1;      // 1M
    u16* wkvst = wqt + 1 * M1;     // 2M
    u16* wkvlt = wkvst + 2 * M1;   // 2M
    u16* wot   = wkvlt + 2 * M1;   // 1M
    u16* qb    = wot + 1 * M1;     // 4M
    u16* ksb   = qb + 4 * M1;      // 4M
    u16* vsb   = ksb + 4 * M1;     // 4M  ([B,16,64,L], pi-permuted tokens)
    u16* klb   = vsb + 4 * M1;     // 4M
    u16* vlb   = klb + 4 * M1;     // 4M  (same)
    u16* attnb = vlb + 4 * M1;     // 4M

    cvt_x<<<4096, 256, 0, stream>>>(x, xb);
    cvt_w_all<<<dim3(192, 32), 256, 0, stream>>>(Wq, Wkvs, Wkvl, Wo,
                                                 wqt, wkvst, wkvlt, wot);
    gemm_proj<<<dim3(40, 32), 256, 0, stream>>>(xb, wqt, wkvst, wkvlt,
                                                qb, ksb, vsb, klb, vlb);
    attn_mfma<<<dim3(16, 8, 4), 256, 0, stream>>>(qb, ksb, vsb, klb, vlb,
                                                  decayf, mixw, attnb);
    gemm_out<<<dim3(8, 64), 256, 0, stream>>>(attnb, wot, (float*)d_out);
}

// Round 9
// 216.544 us; speedup vs baseline: 1.1004x; 1.0101x over previous
//
#include <hip/hip_runtime.h>
#include <hip/hip_bf16.h>
#include <math.h>
#include <stdint.h>

typedef unsigned short u16;
typedef __attribute__((ext_vector_type(8))) short bf16x8;
typedef __attribute__((ext_vector_type(4))) float f32x4;
typedef __attribute__((ext_vector_type(4))) unsigned short u16x4;
typedef __attribute__((ext_vector_type(4))) unsigned int uint32x4;

#define MFMA_BF16(A, B, C) __builtin_amdgcn_mfma_f32_16x16x32_bf16((A), (B), (C), 0, 0, 0)

__device__ __forceinline__ void async16(const void* g, const void* l) {
    __builtin_amdgcn_global_load_lds(
        (const __attribute__((address_space(1))) unsigned int*)(uintptr_t)g,
        (__attribute__((address_space(3))) unsigned int*)(uintptr_t)l, 16, 0, 0);
}

__device__ __forceinline__ u16 f2bf(float f) {
    unsigned u = __float_as_uint(f);
    u += 0x7fffu + ((u >> 16) & 1u);
    return (u16)(u >> 16);
}

__device__ __forceinline__ unsigned pack2(float a, float b) {
    __hip_bfloat162 h = __float22bfloat162_rn(float2{a, b});
    return *reinterpret_cast<unsigned*>(&h);
}

__device__ __forceinline__ float bf2f(u16 v) {
    unsigned u = ((unsigned)v) << 16;
    return __uint_as_float(u);
}

__device__ __forceinline__ bf16x8 mk_frag(unsigned w0, unsigned w1,
                                          unsigned w2, unsigned w3) {
    uint32x4 u = {w0, w1, w2, w3};
    return __builtin_bit_cast(bf16x8, u);
}

// ---------------------------------------------------------------------------
// Converters
// ---------------------------------------------------------------------------
__global__ __launch_bounds__(256) void cvt_x(const float* __restrict__ x,
                                             u16* __restrict__ xb) {
    int i = blockIdx.x * 256 + threadIdx.x;
    float4 v = ((const float4*)x)[i];
    u16x4 o = {f2bf(v.x), f2bf(v.y), f2bf(v.z), f2bf(v.w)};
    ((u16x4*)xb)[i] = o;
}

// All 4 weights fp32 [K=1024][N] -> bf16 [N][1024] in one launch.
__global__ __launch_bounds__(256) void cvt_w_all(
    const float* __restrict__ Wq, const float* __restrict__ Wks,
    const float* __restrict__ Wkl, const float* __restrict__ Wo,
    u16* __restrict__ wqt, u16* __restrict__ wkst,
    u16* __restrict__ wklt, u16* __restrict__ wot)
{
    __shared__ float tile[32][33];
    int x = blockIdx.x;
    const float* W; u16* Wt; int N, nb;
    if (x < 32)       { W = Wq;  Wt = wqt;  N = 1024; nb = x * 32; }
    else if (x < 96)  { W = Wks; Wt = wkst; N = 2048; nb = (x - 32) * 32; }
    else if (x < 160) { W = Wkl; Wt = wklt; N = 2048; nb = (x - 96) * 32; }
    else              { W = Wo;  Wt = wot;  N = 1024; nb = (x - 160) * 32; }
    int kb = blockIdx.y * 32;
    int t = threadIdx.x;
    int r = t >> 3, c4 = (t & 7) * 4;
    float4 v = *(const float4*)&W[(size_t)(kb + r) * N + nb + c4];
    tile[r][c4] = v.x; tile[r][c4 + 1] = v.y;
    tile[r][c4 + 2] = v.z; tile[r][c4 + 3] = v.w;
    __syncthreads();
    u16x4 o = {f2bf(tile[c4 + 0][r]), f2bf(tile[c4 + 1][r]),
               f2bf(tile[c4 + 2][r]), f2bf(tile[c4 + 3][r])};
    *(u16x4*)&Wt[(size_t)(nb + r) * 1024 + kb + c4] = o;
}

// ---------------------------------------------------------------------------
// Fused projection GEMM. Q pre-scaled by 0.125*log2(e).
// Natural dispatch order (col-panel pinned to XCD -> weights L2-hot).
// 128x128 tile, acc 4x4, 2-deep prefetch dbuf, one barrier/step.
// K-type tiles compute C^T -> u16x4 head-major stores. V-type compute C ->
// u16x4 transposed [B,16,64,L] stores, token pi-permuted within 32-blocks
// so attn's PV B-fragment needs no cross-lane shuffle.
// ---------------------------------------------------------------------------
__global__ __launch_bounds__(256, 4) void gemm_proj(
    const u16* __restrict__ A, const u16* __restrict__ wq,
    const u16* __restrict__ wks, const u16* __restrict__ wkl,
    u16* __restrict__ qd, u16* __restrict__ ksd, u16* __restrict__ vsd,
    u16* __restrict__ kld, u16* __restrict__ vld)
{
    __shared__ u16 Alds[2][128][32];   // x rows (tokens)     16 KB
    __shared__ u16 Blds[2][128][32];   // W rows (features)   16 KB

    const int cx = blockIdx.x;
    const int rowBase = blockIdx.y * 128;

    const u16* Bt; u16* dK; u16* dV; int colBase; float osc = 1.0f;
    bool ktype;
    if (cx < 8)       { Bt = wq;  colBase = cx * 128;        dK = qd;  dV = nullptr;
                        osc = 0.18033688f; ktype = true; }
    else if (cx < 24) { Bt = wks; colBase = (cx - 8) * 128;  dK = ksd; dV = vsd;
                        ktype = (cx < 16); }
    else              { Bt = wkl; colBase = (cx - 24) * 128; dK = kld; dV = vld;
                        ktype = (cx < 32); }

    const int t = threadIdx.x;
    const int l = t & 63, w = t >> 6;
    const int wm = w & 1, wn = w >> 1;
    const int lc = l & 15, lr4 = l >> 4;

    f32x4 acc[4][4];
#pragma unroll
    for (int i = 0; i < 4; i++)
#pragma unroll
        for (int j = 0; j < 4; j++) acc[i][j] = (f32x4){0.f, 0.f, 0.f, 0.f};

    const int srow = w * 32 + (l >> 2);
    const int sc8  = (((l & 3) ^ ((l >> 2) & 3)) * 8);
    const u16* Ag = A  + (size_t)(rowBase + srow) * 1024 + sc8;
    const u16* Bg = Bt + (size_t)(colBase + srow) * 1024 + sc8;
    const int sw = (lc & 3);

    auto stage = [&](int kt, int buf) {
        const int ko = kt * 32;
        async16(Ag + ko,         &Alds[buf][w * 32][0]);
        async16(Ag + ko + 16384, &Alds[buf][w * 32 + 16][0]);
        async16(Bg + ko,         &Blds[buf][w * 32][0]);
        async16(Bg + ko + 16384, &Blds[buf][w * 32 + 16][0]);
    };

    stage(0, 0);
    __syncthreads();

    for (int kt = 0; kt < 32; ++kt) {
        const int cur = kt & 1;
        if (kt + 1 < 32) stage(kt + 1, cur ^ 1);

        const u16 (*Lm)[32] = ktype ? Blds[cur] : Alds[cur];
        const u16 (*Ln)[32] = ktype ? Alds[cur] : Blds[cur];

        bf16x8 af[4], bf[4];
#pragma unroll
        for (int mt = 0; mt < 4; ++mt)
            af[mt] = *(const bf16x8*)&Lm[wm * 64 + mt * 16 + lc][(lr4 ^ sw) * 8];
#pragma unroll
        for (int nt = 0; nt < 4; ++nt)
            bf[nt] = *(const bf16x8*)&Ln[wn * 64 + nt * 16 + lc][(lr4 ^ sw) * 8];
#pragma unroll
        for (int mt = 0; mt < 4; ++mt)
#pragma unroll
            for (int nt = 0; nt < 4; ++nt)
                acc[mt][nt] = MFMA_BF16(af[mt], bf[nt], acc[mt][nt]);

        __syncthreads();
    }

    if (ktype) {
        // C^T: m = features, n = tokens. Lane holds 4 consecutive d.
#pragma unroll
        for (int mt = 0; mt < 4; ++mt)
#pragma unroll
            for (int nt = 0; nt < 4; ++nt) {
                int f   = colBase + wm * 64 + mt * 16 + lr4 * 4;
                int tok = rowBase + wn * 64 + nt * 16 + lc;
                int b = tok >> 10, tk = tok & 1023;
                int head = (f >> 6) & 15, d = f & 63;
                u16x4 pv = {f2bf(acc[mt][nt][0] * osc), f2bf(acc[mt][nt][1] * osc),
                            f2bf(acc[mt][nt][2] * osc), f2bf(acc[mt][nt][3] * osc)};
                *(u16x4*)&dK[((size_t)(b * 16 + head) * 1024 + tk) * 64 + d] = pv;
            }
    } else {
        // C: m = tokens, n = features. Transposed V store [B,16,64,L],
        // token index pi-permuted within each 32-block (4-aligned groups).
#pragma unroll
        for (int mt = 0; mt < 4; ++mt)
#pragma unroll
            for (int nt = 0; nt < 4; ++nt) {
                int gr0 = rowBase + wm * 64 + mt * 16 + lr4 * 4;
                int gc0 = colBase + wn * 64 + nt * 16;
                int head = gc0 >> 6;            // 16..31
                int b = gr0 >> 10, tok = gr0 & 1023;
                int tokp = (tok & ~31) | (((tok >> 2) & 3) << 3) |
                           (((tok >> 4) & 1) << 2);
                int d = (gc0 & 63) + lc;
                u16x4 pv = {f2bf(acc[mt][nt][0]), f2bf(acc[mt][nt][1]),
                            f2bf(acc[mt][nt][2]), f2bf(acc[mt][nt][3])};
                *(u16x4*)&dV[((size_t)(b * 16 + head - 16) * 64 + d) * 1024 +
                             tokp] = pv;
            }
    }
}

// ---------------------------------------------------------------------------
// Output GEMM: fp32 C = attn_bf16 x Wo^T, computed as C^T (A=Wo, B=attn).
// 64-token x 128-feature tiles -> 512 blocks (2/CU). float4 stores.
// XCD swizzle + 2-deep prefetch double-buffer.
// ---------------------------------------------------------------------------
__global__ __launch_bounds__(256) void gemm_out(
    const u16* __restrict__ Aattn, const u16* __restrict__ Bwot,
    float* __restrict__ dst)
{
    __shared__ u16 Alds[2][64][32];    // tokens x k     8 KB
    __shared__ u16 Blds[2][128][32];   // features x k  16 KB
    const int t = threadIdx.x;
    const int l = t & 63, w = t >> 6;
    const int wm = w & 1, wn = w >> 1;          // wm: feature half, wn: token half

    const int wg  = blockIdx.y * 8 + blockIdx.x;   // 512 blocks
    const int swz = (wg & 7) * 64 + (wg >> 3);
    const int rowBase = (swz >> 3) * 64;        // tokens
    const int colBase = (swz & 7) * 128;        // features

    const int lc = l & 15, lr4 = l >> 4;

    f32x4 acc[4][2];
#pragma unroll
    for (int i = 0; i < 4; i++)
#pragma unroll
        for (int j = 0; j < 2; j++) acc[i][j] = (f32x4){0.f, 0.f, 0.f, 0.f};

    const int sl  = l >> 2;
    const int sc8 = (((l & 3) ^ (sl & 3)) * 8);
    const u16* Ag = Aattn + (size_t)(rowBase + w * 16 + sl) * 1024 + sc8;
    const u16* Bg = Bwot  + (size_t)(colBase + w * 32 + sl) * 1024 + sc8;
    const int sw = (lc & 3);

    auto stage = [&](int kt, int buf) {
        const int ko = kt * 32;
        async16(Ag + ko,         &Alds[buf][w * 16][0]);
        async16(Bg + ko,         &Blds[buf][w * 32][0]);
        async16(Bg + ko + 16384, &Blds[buf][w * 32 + 16][0]);
    };

    stage(0, 0);
    __syncthreads();

    for (int kt = 0; kt < 32; ++kt) {
        const int cur = kt & 1;
        if (kt + 1 < 32) stage(kt + 1, cur ^ 1);

        bf16x8 af[4], bf[2];
#pragma unroll
        for (int mt = 0; mt < 4; ++mt)
            af[mt] = *(const bf16x8*)&Blds[cur][wm * 64 + mt * 16 + lc][(lr4 ^ sw) * 8];
#pragma unroll
        for (int nt = 0; nt < 2; ++nt)
            bf[nt] = *(const bf16x8*)&Alds[cur][wn * 32 + nt * 16 + lc][(lr4 ^ sw) * 8];
#pragma unroll
        for (int mt = 0; mt < 4; ++mt)
#pragma unroll
            for (int nt = 0; nt < 2; ++nt)
                acc[mt][nt] = MFMA_BF16(af[mt], bf[nt], acc[mt][nt]);

        __syncthreads();
    }

#pragma unroll
    for (int mt = 0; mt < 4; ++mt)
#pragma unroll
        for (int nt = 0; nt < 2; ++nt) {
            int f   = colBase + wm * 64 + mt * 16 + lr4 * 4;
            int tok = rowBase + wn * 32 + nt * 16 + lc;
            float4 v = {acc[mt][nt][0], acc[mt][nt][1],
                        acc[mt][nt][2], acc[mt][nt][3]};
            *(float4*)&dst[(size_t)tok * 1024 + f] = v;
        }
}

// ---------------------------------------------------------------------------
// Flash attention, transposed-MFMA (S^T, O^T), K/V double-buffered prefetch,
// one barrier/iter. Zero-shuffle PV (pack2 words ARE the PV B-fragment; V
// pi-permuted by producer). Decay folded into MFMA C-init. Both branches
// fused + in-register mix (R8).
//
// R9: q-tile 128 -> 64 rows. R8's fusion halved co-residency (512 blocks =
// 2/CU grid-limited, 25% static occupancy) in a latency-bound kernel.
// Now each wave owns ONE 16-row q-group (qg dim deleted): grid 16x16x4 =
// 1024 blocks = 4/CU (50% static). Per-wave state ~halves (~100 regs ->
// launch_bounds(256,4)). Total MFMA/exp work invariant (half per iter x
// twice the blocks); staging/LDS-read volume doubles but stays far under
// the pipe ceilings (~9 TB/s L2/L3, ~34 vs 69 TB/s LDS).
// Branch-0 window keeps the old element margins: ktLo=qt-7, ktHi=qt+9.
// ---------------------------------------------------------------------------
__global__ __launch_bounds__(256, 4) void attn_mfma(
    const u16* __restrict__ Q, const u16* __restrict__ Ksb,
    const u16* __restrict__ Vsb, const u16* __restrict__ Klb,
    const u16* __restrict__ Vlb, const float* __restrict__ decayf,
    const float* __restrict__ mixw, u16* __restrict__ dst)
{
    __shared__ __align__(16) u16 Kt[2][2][64][32];  // [buf][d-half][krow][32d]
    __shared__ __align__(16) u16 Vt[2][2][64][32];  // [buf][k-half][d][32krow]

    const int t = threadIdx.x;
    const int l = t & 63, w = t >> 6;
    const int lc = l & 15, lr4 = l >> 4;
    const int h = blockIdx.x, qt = blockIdx.y, b = blockIdx.z;
    const size_t bh = (size_t)(b * 16 + h);
    const int qbase = qt * 64;
    const u16* Qg = Q + bh * (1024 * 64);

    const int sl = l >> 2;
    const int sc = (((l & 3) ^ ((l >> 3) & 3)) * 8);
    const int swr = (lc >> 1) & 3;

    // ---- Q B-operand fragment (one 16-row group per wave) ----
    bf16x8 aQ[2];
#pragma unroll
    for (int kh = 0; kh < 2; ++kh)
        aQ[kh] = *(const bf16x8*)&Qg[
            (size_t)(qbase + w * 16 + lc) * 64 + kh * 32 + lr4 * 8];

    const float C2 = (1.0f - decayf[0]) * 1.44269504f;
    const float alpha = 1.0f / (1.0f + __expf(-mixw[0]));
    const float qf = (float)(qbase + w * 16 + lc);

    uint2 w0[4];  // branch-0 normalized output, bf16-packed

#pragma unroll
    for (int br = 0; br < 2; ++br) {
        const u16* Kg = (br ? Klb : Ksb) + bh * (1024 * 64);
        const u16* Vg = (br ? Vlb : Vsb) + bh * (64 * 1024);

        // branch-0 range: only k-tiles with |q - k| < ~450 matter
        int ktLo = 0, ktHi = 16;
        if (br == 0) {
            ktLo = qt - 7; if (ktLo < 0) ktLo = 0;
            ktHi = qt + 9; if (ktHi > 16) ktHi = 16;
        }

        auto stage = [&](int kt, int buf) {
#pragma unroll
            for (int i = 0; i < 4; i++) {
                int id = w * 4 + i;
                int kh = (id >> 2) & 1, ch = id & 3;
                if (id < 8)
                    async16(Kg + (size_t)(kt * 64 + ch * 16 + sl) * 64 + kh * 32 + sc,
                            &Kt[buf][kh][ch * 16][0]);
                else
                    async16(Vg + (size_t)(ch * 16 + sl) * 1024 + kt * 64 + kh * 32 + sc,
                            &Vt[buf][kh][ch * 16][0]);
            }
        };

        f32x4 sumv = (f32x4){0.f, 0.f, 0.f, 0.f};
        f32x4 o[4];
#pragma unroll
        for (int dt = 0; dt < 4; ++dt) o[dt] = (f32x4){0.f, 0.f, 0.f, 0.f};

        stage(ktLo, 0);
        __syncthreads();

        for (int kt = ktLo, it = 0; kt < ktHi; ++kt, ++it) {
            const int cur = it & 1;
            if (kt + 1 < ktHi) stage(kt + 1, cur ^ 1);

            bf16x8 ak[4][2];
#pragma unroll
            for (int nt = 0; nt < 4; ++nt) {
                ak[nt][0] = *(const bf16x8*)&Kt[cur][0][nt * 16 + lc][(lr4 ^ swr) * 8];
                ak[nt][1] = *(const bf16x8*)&Kt[cur][1][nt * 16 + lc][(lr4 ^ swr) * 8];
            }

            unsigned pw[8];
            {
                const float d0 = qf + (float)(-kt * 64 - lr4 * 4);
                f32x4 s[4];
#pragma unroll
                for (int nt = 0; nt < 4; ++nt) {
                    if (br == 0) {
                        float dd = d0 - (float)(nt * 16);
                        s[nt] = (f32x4){-fabsf(dd) * C2,
                                        -fabsf(dd - 1.0f) * C2,
                                        -fabsf(dd - 2.0f) * C2,
                                        -fabsf(dd - 3.0f) * C2};
                    } else {
                        s[nt] = (f32x4){0.f, 0.f, 0.f, 0.f};
                    }
                    s[nt] = MFMA_BF16(ak[nt][0], aQ[0], s[nt]);
                    s[nt] = MFMA_BF16(ak[nt][1], aQ[1], s[nt]);
                }
#pragma unroll
                for (int nt = 0; nt < 4; ++nt) {
                    float p0 = __builtin_amdgcn_exp2f(s[nt][0]);
                    float p1 = __builtin_amdgcn_exp2f(s[nt][1]);
                    float p2 = __builtin_amdgcn_exp2f(s[nt][2]);
                    float p3 = __builtin_amdgcn_exp2f(s[nt][3]);
                    sumv[0] += p0; sumv[1] += p1;
                    sumv[2] += p2; sumv[3] += p3;
                    pw[nt * 2]     = pack2(p0, p1);
                    pw[nt * 2 + 1] = pack2(p2, p3);
                }
            }

            bf16x8 pb0 = mk_frag(pw[0], pw[1], pw[2], pw[3]);
            bf16x8 pb1 = mk_frag(pw[4], pw[5], pw[6], pw[7]);
#pragma unroll
            for (int dt = 0; dt < 4; ++dt) {
                bf16x8 v0 = *(const bf16x8*)&Vt[cur][0][dt * 16 + lc][(lr4 ^ swr) * 8];
                bf16x8 v1 = *(const bf16x8*)&Vt[cur][1][dt * 16 + lc][(lr4 ^ swr) * 8];
                o[dt] = MFMA_BF16(v0, pb0, o[dt]);
                o[dt] = MFMA_BF16(v1, pb1, o[dt]);
            }

            __syncthreads();
        }

        // ---- normalize; br0 packs to bf16, br1 mixes and stores ----
        {
            float s = (sumv[0] + sumv[1]) + (sumv[2] + sumv[3]);
            s += __shfl_xor(s, 16);
            s += __shfl_xor(s, 32);
            float inv = 1.0f / s;
            if (br == 0) {
#pragma unroll
                for (int dt = 0; dt < 4; ++dt)
                    w0[dt] = uint2{
                        pack2(o[dt][0] * inv, o[dt][1] * inv),
                        pack2(o[dt][2] * inv, o[dt][3] * inv)};
            } else {
                int qrow = qbase + w * 16 + lc;
                u16* op = dst + ((size_t)(b * 1024) + qrow) * 1024 + h * 64;
#pragma unroll
                for (int dt = 0; dt < 4; ++dt) {
                    float s0 = bf2f((u16)(w0[dt].x));
                    float s1 = bf2f((u16)(w0[dt].x >> 16));
                    float s2 = bf2f((u16)(w0[dt].y));
                    float s3 = bf2f((u16)(w0[dt].y >> 16));
                    float l0 = o[dt][0] * inv, l1 = o[dt][1] * inv;
                    float l2 = o[dt][2] * inv, l3 = o[dt][3] * inv;
                    uint2 w2 = {pack2(l0 + alpha * (s0 - l0),
                                      l1 + alpha * (s1 - l1)),
                                pack2(l2 + alpha * (s2 - l2),
                                      l3 + alpha * (s3 - l3))};
                    *(uint2*)&op[dt * 16 + lr4 * 4] = w2;
                }
            }
        }
    }
}

// ---------------------------------------------------------------------------
extern "C" void kernel_launch(void* const* d_in, const int* in_sizes, int n_in,
                              void* d_out, int out_size, void* d_ws, size_t ws_size,
                              hipStream_t stream) {
    const float* x      = (const float*)d_in[0];
    const float* Wq     = (const float*)d_in[1];
    const float* Wkvs   = (const float*)d_in[2];
    const float* Wkvl   = (const float*)d_in[3];
    const float* Wo     = (const float*)d_in[4];
    const float* mixw   = (const float*)d_in[5];
    const float* decayf = (const float*)d_in[6];

    const size_t M1 = 1024 * 1024;
    u16* ws    = (u16*)d_ws;
    u16* xb    = ws;               // 4M
    u16* wqt   = xb + 4 * M1;      // 1M
    u16* wkvst = wqt + 1 * M1;     // 2M
    u16* wkvlt = wkvst + 2 * M1;   // 2M
    u16* wot   = wkvlt + 2 * M1;   // 1M
    u16* qb    = wot + 1 * M1;     // 4M
    u16* ksb   = qb + 4 * M1;      // 4M
    u16* vsb   = ksb + 4 * M1;     // 4M  ([B,16,64,L], pi-permuted tokens)
    u16* klb   = vsb + 4 * M1;     // 4M
    u16* vlb   = klb + 4 * M1;     // 4M  (same)
    u16* attnb = vlb + 4 * M1;     // 4M

    cvt_x<<<4096, 256, 0, stream>>>(x, xb);
    cvt_w_all<<<dim3(192, 32), 256, 0, stream>>>(Wq, Wkvs, Wkvl, Wo,
                                                 wqt, wkvst, wkvlt, wot);
    gemm_proj<<<dim3(40, 32), 256, 0, stream>>>(xb, wqt, wkvst, wkvlt,
                                                qb, ksb, vsb, klb, vlb);
    attn_mfma<<<dim3(16, 16, 4), 256, 0, stream>>>(qb, ksb, vsb, klb, vlb,
                                                   decayf, mixw, attnb);
    gemm_out<<<dim3(8, 64), 256, 0, stream>>>(attnb, wot, (float*)d_out);
}